// Round 10
// baseline (423.206 us; speedup 1.0000x reference)
//
#include <hip/hip_runtime.h>

typedef __attribute__((ext_vector_type(8))) __bf16 b16x8;
typedef __attribute__((ext_vector_type(4))) float f32x4;
typedef unsigned short u16;
typedef unsigned int u32;

#define MFMA16(a, b, c) __builtin_amdgcn_mfma_f32_16x16x32_bf16((a), (b), (c), 0, 0, 0)
// XOR swizzle: spread 16B slots across banks for row-major bf16 tiles w/ 256B row stride
#define SW(byteoff, row) ((byteoff) ^ (((row) & 7) << 4))
#define LOG2E 1.4426950408889634f

__device__ __forceinline__ u16 f2bf_bits(float f) {
  union { float f; unsigned u; } v; v.f = f;
  unsigned r = (v.u + 0x7FFFu + ((v.u >> 16) & 1u)) >> 16;
  return (u16)r;
}
__device__ __forceinline__ float rcp_f(float x) { float r; asm("v_rcp_f32 %0, %1" : "=v"(r) : "v"(x)); return r; }
__device__ __forceinline__ float exp2_f(float x) { float r; asm("v_exp_f32 %0, %1" : "=v"(r) : "v"(x)); return r; }
__device__ __forceinline__ f32x4 fzero4() { f32x4 z; z[0]=0.f; z[1]=0.f; z[2]=0.f; z[3]=0.f; return z; }
__device__ __forceinline__ b16x8 bzero8() {
  b16x8 z;
  #pragma unroll
  for (int j = 0; j < 8; ++j) z[j] = (__bf16)0.f;
  return z;
}
// barrier that drains only LDS (no vmcnt drain): loads/stores fly across
__device__ __forceinline__ void bar_lgkm() {
  asm volatile("s_waitcnt lgkmcnt(0)\n\ts_barrier" ::: "memory");
}
// LSTM cell elementwise; gate pre-activations (incl. bias) already scaled by log2e
__device__ __forceinline__ void cellf(float gi, float gf, float gg, float go,
                                      float& cc, float& hv) {
  float si = rcp_f(1.f + exp2_f(-gi));
  float sf = rcp_f(1.f + exp2_f(-gf));
  float tg = 1.f - 2.f * rcp_f(1.f + exp2_f(gg + gg));
  float cn = sf * cc + si * tg;
  float so = rcp_f(1.f + exp2_f(-go));
  float tc = 1.f - 2.f * rcp_f(1.f + exp2_f(2.8853900817779268f * cn));
  cc = cn; hv = so * tc;
}

// ---------------- prep: weights -> bf16 (gate weights pre-scaled by log2e) ----------------
__global__ __launch_bounds__(256) void prep_kernel(
    const float* __restrict__ W1, const float* __restrict__ W2,
    const float* __restrict__ Wih, const float* __restrict__ Whh,
    const float* __restrict__ Wp, const float* __restrict__ Wv,
    const float* __restrict__ bih, const float* __restrict__ bhh,
    u16* __restrict__ W1b, u16* __restrict__ W2b, u16* __restrict__ Wihb,
    u16* __restrict__ Whhb, u16* __restrict__ Whb, float* __restrict__ gbp)
{
  int i = blockIdx.x * 256 + threadIdx.x;   // grid 256*256 = 65536
  if (i < 8192) {                            // W1 padded (128 x 64), K 54->64
    int r = i >> 6, k = i & 63;
    W1b[i] = f2bf_bits(k < 54 ? W1[r * 54 + k] : 0.f);
  }
  if (i < 16384) W2b[i] = f2bf_bits(W2[i]);  // 128x128
  Wihb[i] = f2bf_bits(LOG2E * Wih[i]);       // 512x128, pre-scaled
  Whhb[i] = f2bf_bits(LOG2E * Whh[i]);       // 512x128, pre-scaled
  if (i < 2048) {                            // head: rows 0-5 Wp, 6 Wv, 7-15 zero (16x128)
    int r = i >> 7, k = i & 127;
    float v = (r < 6) ? Wp[r * 128 + k] : ((r == 6) ? Wv[k] : 0.f);
    Whb[i] = f2bf_bits(v);                   // NOT scaled
  }
  if (i < 512) gbp[i] = LOG2E * (bih[i] + bhh[i]);
}

// ---------------- fused MLP + LSTM recurrence + heads ----------------
// 256 blocks x 8 batch rows, 512 threads (8 waves); wave w owns gate cols [16w,16w+16)
// AND MLP N-tile nt=w. Per step t: X1(t+3) computed from obs registers PRELOADED at
// step t-1 (OBSLOAD(t+4) issued at top of step t -> one full step of latency cover);
// X2(t+2) from the X1 ring; gate-input x consumed from LDS; x-MFMAs for t+1
// pre-issued before the barrier. h_t -> LDS ring + global H (never read in-loop ->
// no vmcnt drain); heads after the loop from L2-hot H.
__global__ __launch_bounds__(512) void lstm_fused_kernel(
    const float* __restrict__ obs, const float* __restrict__ h0, const float* __restrict__ c0,
    const int* __restrict__ done,
    const u16* __restrict__ W1b, const u16* __restrict__ W2b,
    const u16* __restrict__ Wihb, const u16* __restrict__ Whhb, const u16* __restrict__ Whb,
    const float* __restrict__ gb, const float* __restrict__ b1v, const float* __restrict__ b2v,
    const float* __restrict__ bp, const float* __restrict__ bv,
    u16* __restrict__ H, float* __restrict__ out)
{
  __shared__ u16 hbuf[2][8 * 128];   // ping-pong h tiles (swizzled)
  __shared__ u16 x1tl[2][8 * 128];   // X1 ring (swizzled)
  __shared__ u16 xtl[2][8 * 128];    // X2 (gate-input x) ring (swizzled)
  __shared__ int dsh[1024];          // done[t][0..7] staged
  const int tid = threadIdx.x;
  const int w   = tid >> 6;
  const int l   = tid & 63;
  const int col = l & 15;
  const int q   = l >> 4;
  const int cl  = col & 7;
  const int n0  = blockIdx.x * 8;    // 256 blocks * 8 rows = 2048
  const int rbase = ((q & 1) << 2) + ((q >> 1) << 1);

  // resident gate-weight fragments (pre-scaled by log2e)
  b16x8 wih[4][4], whh[4][4];
  #pragma unroll
  for (int g = 0; g < 4; ++g) {
    int nt = 8 * g + w;
    #pragma unroll
    for (int c = 0; c < 4; ++c) {
      wih[g][c] = *(const b16x8*)(Wihb + (nt * 16 + col) * 128 + 8 * q + 32 * c);
      whh[g][c] = *(const b16x8*)(Whhb + (nt * 16 + col) * 128 + 8 * q + 32 * c);
    }
  }
  float gbr[4];
  #pragma unroll
  for (int g = 0; g < 4; ++g) gbr[g] = gb[(8 * g + w) * 16 + col];

  // resident MLP weight fragments for N-tile nt=w
  b16x8 w1f[2], w2f[4];
  #pragma unroll
  for (int c = 0; c < 2; ++c) w1f[c] = *(const b16x8*)(W1b + (w * 16 + col) * 64 + 8 * q + 32 * c);
  #pragma unroll
  for (int c = 0; c < 4; ++c) w2f[c] = *(const b16x8*)(W2b + (w * 16 + col) * 128 + 8 * q + 32 * c);
  const float b1r = b1v[w * 16 + col];
  const float b2r = b2v[w * 16 + col];

  // c-state
  float cc0 = c0[(n0 + rbase) * 128 + 16 * w + col];
  float cc1 = c0[(n0 + rbase + 1) * 128 + 16 * w + col];

  // stage h0 -> hbuf[0]; done -> dsh
  #pragma unroll
  for (int j = 0; j < 2; ++j) {
    int idx = tid * 2 + j;
    int row = idx >> 7, k = idx & 127;
    *(u16*)((char*)hbuf[0] + SW(row * 256 + k * 2, row)) = f2bf_bits(h0[(n0 + row) * 128 + k]);
    dsh[idx] = done[(idx >> 3) * 2048 + n0 + (idx & 7)];
  }

  // loop-invariant LDS offsets
  int offr[4];
  #pragma unroll
  for (int c = 0; c < 4; ++c) offr[c] = SW(cl * 256 + 16 * q + 64 * c, cl);
  const int wcol2 = (16 * w + col) * 2;
  const int offw0 = SW(rbase * 256 + wcol2, rbase);
  const int offw1 = SW((rbase + 1) * 256 + wcol2, rbase + 1);
  int swoff[4];                      // MLP output writes: rows m=4q+r (valid q<2), col 16w+col
  #pragma unroll
  for (int r = 0; r < 4; ++r) { int m = 4 * q + r; swoff[r] = SW(m * 256 + wcol2, m); }

  // obs addressing: lane reads row n0+cl, k = 32c+8q+2p (pairs; clamped+zeroed >=54)
  const long obl = (long)(n0 + cl) * 54;
  int koff[8]; bool kval[8];
  #pragma unroll
  for (int c = 0; c < 2; ++c)
    #pragma unroll
    for (int p = 0; p < 4; ++p) {
      int i = c * 4 + p, kk = 32 * c + 8 * q + 2 * p;
      kval[i] = (kk < 54); koff[i] = kval[i] ? kk : 0;
    }

  // H store pointers
  u16* hp0 = H + (long)(n0 + rbase) * 128 + 16 * w + col;
  u16* hp1 = H + (long)(n0 + rbase + 1) * 128 + 16 * w + col;

  // ---- MLP phase helpers ----
  auto OBSLOAD = [&](int T, float2 (&o)[8]) {
    const float* obsT = obs + (long)T * 110592 + obl;
    #pragma unroll
    for (int i = 0; i < 8; ++i) o[i] = *(const float2*)(obsT + koff[i]);
  };
  auto X1COMP = [&](const float2 (&o)[8], u16* dst) {
    b16x8 a0[2];
    #pragma unroll
    for (int c = 0; c < 2; ++c)
      #pragma unroll
      for (int p = 0; p < 4; ++p) {
        int i = c * 4 + p;
        a0[c][2 * p]     = (__bf16)(kval[i] ? o[i].x : 0.f);
        a0[c][2 * p + 1] = (__bf16)(kval[i] ? o[i].y : 0.f);
      }
    f32x4 a = fzero4();
    a = MFMA16(a0[0], w1f[0], a);
    a = MFMA16(a0[1], w1f[1], a);
    if (q < 2) {
      #pragma unroll
      for (int r = 0; r < 4; ++r)
        *(u16*)((char*)dst + swoff[r]) = f2bf_bits(fmaxf(a[r] + b1r, 0.f));
    }
  };
  auto MLPX1 = [&](int T, u16* dst) { float2 o[8]; OBSLOAD(T, o); X1COMP(o, dst); };
  auto MLPX2 = [&](const u16* src, u16* dst) {
    b16x8 a1[4];
    #pragma unroll
    for (int c = 0; c < 4; ++c) a1[c] = *(const b16x8*)((const char*)src + offr[c]);
    f32x4 a = fzero4();
    #pragma unroll
    for (int c = 0; c < 4; ++c) a = MFMA16(a1[c], w2f[c], a);
    if (q < 2) {
      #pragma unroll
      for (int r = 0; r < 4; ++r)
        *(u16*)((char*)dst + swoff[r]) = f2bf_bits(fmaxf(a[r] + b2r, 0.f));
    }
  };

  // obs prefetch registers (ping-pong, one step ahead)
  float2 oA[8], oB[8];

  // ---- prologue: X1(0,1,2), X2(0,1), accA = bias + x(0), oA = obs(3) ----
  OBSLOAD(3, oA);                          // for step 0's X1(3)
  __syncthreads();                         // h0/dsh staged
  MLPX1(0, x1tl[0]); MLPX1(1, x1tl[1]);
  __syncthreads();                         // x1 tiles visible
  MLPX2(x1tl[0], xtl[0]); MLPX2(x1tl[1], xtl[1]);
  __syncthreads();                         // x tiles visible
  MLPX1(2, x1tl[0]);
  f32x4 accA[4], accB[4];
  {
    b16x8 xa[4];
    #pragma unroll
    for (int c = 0; c < 4; ++c) xa[c] = *(const b16x8*)((const char*)xtl[0] + offr[c]);
    #pragma unroll
    for (int g = 0; g < 4; ++g) { f32x4 z; z[0]=gbr[g]; z[1]=gbr[g]; z[2]=gbr[g]; z[3]=gbr[g]; accA[g] = z; }
    #pragma unroll
    for (int g = 0; g < 4; ++g)
      #pragma unroll
      for (int c = 0; c < 4; ++c)
        accA[g] = MFMA16(xa[c], wih[g][c], accA[g]);
  }
  __syncthreads();                         // X1(2) visible; enter loop

  int dA = 0, dC0 = 0, dC1 = 0;
  float hv0 = 0.f, hv1 = 0.f;

// one fused step. OC holds obs(T+3) (loaded last step); ON gets obs(T+4) issued at top.
// X1R=X1(T+2) read by X2 phase; X1W gets X1(T+3); XTR=x(T+1) (pre-MFMA read);
// XTW gets x(T+2). AC holds bias+x(T_); AN pre-filled for T_+1.
#define LSTEP(T_, RB, WB, AC, AN, X1R, X1W, XTR, XTW, OC, ON) {                      \
    { int t4 = (T_) + 4; if (t4 > 127) t4 = 127; OBSLOAD(t4, ON); }                  \
    b16x8 ha[4];                                                                     \
    _Pragma("unroll") for (int c = 0; c < 4; ++c) {                                  \
      ha[c] = *(const b16x8*)((const char*)(RB) + offr[c]);                          \
      if (dA) ha[c] = bzero8();                                                      \
    }                                                                                \
    if (dC0) cc0 = 0.f;                                                              \
    if (dC1) cc1 = 0.f;                                                              \
    __builtin_amdgcn_s_setprio(1);                                                   \
    _Pragma("unroll") for (int g = 0; g < 4; ++g)                                    \
      _Pragma("unroll") for (int c = 0; c < 4; ++c)                                  \
        AC[g] = MFMA16(ha[c], whh[g][c], AC[g]);                                     \
    __builtin_amdgcn_s_setprio(0);                                                   \
    dA  = dsh[(T_) * 8 + cl];                                                        \
    dC0 = dsh[(T_) * 8 + rbase];                                                     \
    dC1 = dsh[(T_) * 8 + rbase + 1];                                                 \
    _Pragma("unroll") for (int g = 0; g < 4; ++g) {                                  \
      asm volatile("v_permlane32_swap_b32 %0, %1" : "+v"(AC[g][0]), "+v"(AC[g][2])); \
      asm volatile("v_permlane32_swap_b32 %0, %1" : "+v"(AC[g][1]), "+v"(AC[g][3])); \
    }                                                                                \
    cellf(AC[0][0], AC[1][0], AC[2][0], AC[3][0], cc0, hv0);                         \
    cellf(AC[0][1], AC[1][1], AC[2][1], AC[3][1], cc1, hv1);                         \
    { u32 pk;                                                                        \
      asm("v_cvt_pk_bf16_f32 %0, %1, %2" : "=v"(pk) : "v"(hv0), "v"(hv1));           \
      *(u16*)((char*)(WB) + offw0) = (u16)pk;                                        \
      *(u16*)((char*)(WB) + offw1) = (u16)(pk >> 16);                                \
      *hp0 = (u16)pk; *hp1 = (u16)(pk >> 16);                                        \
      hp0 += 262144; hp1 += 262144; }                                                \
    X1COMP(OC, X1W);                                                                 \
    MLPX2(X1R, XTW);                                                                 \
    { b16x8 xa[4];                                                                   \
      _Pragma("unroll") for (int c = 0; c < 4; ++c)                                  \
        xa[c] = *(const b16x8*)((const char*)(XTR) + offr[c]);                       \
      _Pragma("unroll") for (int g = 0; g < 4; ++g) {                                \
        f32x4 z; z[0]=gbr[g]; z[1]=gbr[g]; z[2]=gbr[g]; z[3]=gbr[g]; AN[g] = z; }    \
      __builtin_amdgcn_s_setprio(1);                                                 \
      _Pragma("unroll") for (int g = 0; g < 4; ++g)                                  \
        _Pragma("unroll") for (int c = 0; c < 4; ++c)                                \
          AN[g] = MFMA16(xa[c], wih[g][c], AN[g]);                                   \
      __builtin_amdgcn_s_setprio(0);                                                 \
    }                                                                                \
    bar_lgkm();                                                                      \
  }

  for (int tb = 0; tb < 128; tb += 2) {
    LSTEP(tb,     hbuf[0], hbuf[1], accA, accB, x1tl[0], x1tl[1], xtl[1], xtl[0], oA, oB)
    LSTEP(tb + 1, hbuf[1], hbuf[0], accB, accA, x1tl[1], x1tl[0], xtl[0], xtl[1], oB, oA)
  }
#undef LSTEP

  // final hT / cT (f32), 2 rows per lane
  {
    int k = 16 * w + col;
    out[1835008 + (n0 + rbase) * 128 + k]     = hv0;
    out[1835008 + (n0 + rbase + 1) * 128 + k] = hv1;
    out[2097152 + (n0 + rbase) * 128 + k]     = cc0;
    out[2097152 + (n0 + rbase + 1) * 128 + k] = cc1;
  }

  // drain all H stores from every wave, then compute heads from own (L2-hot) H slice
  __syncthreads();
  {
    b16x8 wh[4];
    #pragma unroll
    for (int c = 0; c < 4; ++c) wh[c] = *(const b16x8*)(Whb + col * 128 + 8 * q + 32 * c);
    const float hb = (col < 6) ? bp[col] : ((col == 6) ? bv[0] : 0.f);
    #pragma unroll
    for (int i = 0; i < 8; ++i) {
      int t0 = 16 * w + 2 * i;
      const u16* hsrc = H + ((long)(t0 + (col >> 3)) * 2048 + n0 + (col & 7)) * 128 + 8 * q;
      b16x8 a[4];
      #pragma unroll
      for (int c = 0; c < 4; ++c) a[c] = *(const b16x8*)(hsrc + 32 * c);
      f32x4 hacc = fzero4();
      #pragma unroll
      for (int c = 0; c < 4; ++c) hacc = MFMA16(a[c], wh[c], hacc);
      #pragma unroll
      for (int r = 0; r < 4; ++r) {
        int m = 4 * q + r;
        int tt = t0 + (m >> 3);
        int n = n0 + (m & 7);
        float v = hacc[r] + hb;
        if (col < 6)       out[(tt * 2048 + n) * 6 + col] = v;
        else if (col == 6) out[1572864 + tt * 2048 + n] = v;
      }
    }
  }
}

extern "C" void kernel_launch(void* const* d_in, const int* in_sizes, int n_in,
                              void* d_out, int out_size, void* d_ws, size_t ws_size,
                              hipStream_t stream) {
  const float* obs  = (const float*)d_in[0];
  const float* h0   = (const float*)d_in[1];
  const float* c0   = (const float*)d_in[2];
  const int*   done = (const int*)d_in[3];
  const float* W1   = (const float*)d_in[4];
  const float* b1   = (const float*)d_in[5];
  const float* W2   = (const float*)d_in[6];
  const float* b2   = (const float*)d_in[7];
  const float* Wih  = (const float*)d_in[8];
  const float* Whh  = (const float*)d_in[9];
  const float* bih  = (const float*)d_in[10];
  const float* bhh  = (const float*)d_in[11];
  const float* Wp   = (const float*)d_in[12];
  const float* bp   = (const float*)d_in[13];
  const float* Wv   = (const float*)d_in[14];
  const float* bv   = (const float*)d_in[15];

  char* ws = (char*)d_ws;
  u16*   H    = (u16*)(ws);                                      // 67108864 B
  u16*   W1b  = (u16*)(ws + 67108864);                           // 16384 B
  u16*   W2b  = (u16*)(ws + 67108864 + 16384);                   // 32768 B
  u16*   Wihb = (u16*)(ws + 67108864 + 16384 + 32768);           // 131072 B
  u16*   Whhb = (u16*)(ws + 67108864 + 16384 + 32768 + 131072);  // 131072 B
  u16*   Whb  = (u16*)(ws + 67108864 + 16384 + 32768 + 262144);  // 4096 B
  float* gbp  = (float*)(ws + 67108864 + 16384 + 32768 + 262144 + 4096);
  float* out  = (float*)d_out;

  hipLaunchKernelGGL(prep_kernel, dim3(256), dim3(256), 0, stream,
                     W1, W2, Wih, Whh, Wp, Wv, bih, bhh, W1b, W2b, Wihb, Whhb, Whb, gbp);
  hipLaunchKernelGGL(lstm_fused_kernel, dim3(256), dim3(512), 0, stream,
                     obs, h0, c0, done, W1b, W2b, Wihb, Whhb, Whb, gbp, b1, b2, bp, bv, H, out);
}

// Round 11
// 422.038 us; speedup vs baseline: 1.0028x; 1.0028x over previous
//
#include <hip/hip_runtime.h>

typedef __attribute__((ext_vector_type(8))) __bf16 b16x8;
typedef __attribute__((ext_vector_type(4))) float f32x4;
typedef unsigned short u16;
typedef unsigned int u32;

#define MFMA16(a, b, c) __builtin_amdgcn_mfma_f32_16x16x32_bf16((a), (b), (c), 0, 0, 0)
// XOR swizzle: spread 16B slots across banks for row-major bf16 tiles w/ 256B row stride
#define SW(byteoff, row) ((byteoff) ^ (((row) & 7) << 4))
#define LOG2E 1.4426950408889634f

__device__ __forceinline__ u16 f2bf_bits(float f) {
  union { float f; unsigned u; } v; v.f = f;
  unsigned r = (v.u + 0x7FFFu + ((v.u >> 16) & 1u)) >> 16;
  return (u16)r;
}
__device__ __forceinline__ float rcp_f(float x) { float r; asm("v_rcp_f32 %0, %1" : "=v"(r) : "v"(x)); return r; }
__device__ __forceinline__ float exp2_f(float x) { float r; asm("v_exp_f32 %0, %1" : "=v"(r) : "v"(x)); return r; }
__device__ __forceinline__ f32x4 fzero4() { f32x4 z; z[0]=0.f; z[1]=0.f; z[2]=0.f; z[3]=0.f; return z; }
__device__ __forceinline__ b16x8 bzero8() {
  b16x8 z;
  #pragma unroll
  for (int j = 0; j < 8; ++j) z[j] = (__bf16)0.f;
  return z;
}
// barrier that drains only LDS (no vmcnt drain): loads/stores fly across
__device__ __forceinline__ void bar_lgkm() {
  asm volatile("s_waitcnt lgkmcnt(0)\n\ts_barrier" ::: "memory");
}
// LSTM cell elementwise; gate pre-activations (incl. bias) already scaled by log2e
__device__ __forceinline__ void cellf(float gi, float gf, float gg, float go,
                                      float& cc, float& hv) {
  float si = rcp_f(1.f + exp2_f(-gi));
  float sf = rcp_f(1.f + exp2_f(-gf));
  float tg = 1.f - 2.f * rcp_f(1.f + exp2_f(gg + gg));
  float cn = sf * cc + si * tg;
  float so = rcp_f(1.f + exp2_f(-go));
  float tc = 1.f - 2.f * rcp_f(1.f + exp2_f(2.8853900817779268f * cn));
  cc = cn; hv = so * tc;
}

// ---------------- prep: weights -> bf16 (gate weights pre-scaled by log2e) ----------------
__global__ __launch_bounds__(256) void prep_kernel(
    const float* __restrict__ W1, const float* __restrict__ W2,
    const float* __restrict__ Wih, const float* __restrict__ Whh,
    const float* __restrict__ Wp, const float* __restrict__ Wv,
    const float* __restrict__ bih, const float* __restrict__ bhh,
    u16* __restrict__ W1b, u16* __restrict__ W2b, u16* __restrict__ Wihb,
    u16* __restrict__ Whhb, u16* __restrict__ Whb, float* __restrict__ gbp)
{
  int i = blockIdx.x * 256 + threadIdx.x;   // grid 256*256 = 65536
  if (i < 8192) {                            // W1 padded (128 x 64), K 54->64
    int r = i >> 6, k = i & 63;
    W1b[i] = f2bf_bits(k < 54 ? W1[r * 54 + k] : 0.f);
  }
  if (i < 16384) W2b[i] = f2bf_bits(W2[i]);  // 128x128
  Wihb[i] = f2bf_bits(LOG2E * Wih[i]);       // 512x128, pre-scaled
  Whhb[i] = f2bf_bits(LOG2E * Whh[i]);       // 512x128, pre-scaled
  if (i < 2048) {                            // head: rows 0-5 Wp, 6 Wv, 7-15 zero (16x128)
    int r = i >> 7, k = i & 127;
    float v = (r < 6) ? Wp[r * 128 + k] : ((r == 6) ? Wv[k] : 0.f);
    Whb[i] = f2bf_bits(v);                   // NOT scaled
  }
  if (i < 512) gbp[i] = LOG2E * (bih[i] + bhh[i]);
}

// ---------------- fused MLP + LSTM recurrence + heads ----------------
// 256 blocks x 8 batch rows, 512 threads (8 waves); wave w owns gate cols [16w,16w+16)
// AND MLP N-tile nt=w. Per step t: X1(t+3) computed from obs registers PRELOADED at
// step t-1 (OBSLOAD(t+4) issued at top of step t -> one full step of latency cover);
// X2(t+2) from the X1 ring; gate-input x consumed from LDS; x-MFMAs for t+1
// pre-issued before the barrier. h_t -> LDS ring + global H (never read in-loop ->
// no vmcnt drain); heads after the loop from L2-hot H.
// __launch_bounds__(512,2): min 2 waves/EU -> 256-reg unified budget/wave. Without
// this the allocator caps at 128 arch-VGPR and SPILLS the obs prefetch (r10: 457us).
__global__ __launch_bounds__(512, 2) void lstm_fused_kernel(
    const float* __restrict__ obs, const float* __restrict__ h0, const float* __restrict__ c0,
    const int* __restrict__ done,
    const u16* __restrict__ W1b, const u16* __restrict__ W2b,
    const u16* __restrict__ Wihb, const u16* __restrict__ Whhb, const u16* __restrict__ Whb,
    const float* __restrict__ gb, const float* __restrict__ b1v, const float* __restrict__ b2v,
    const float* __restrict__ bp, const float* __restrict__ bv,
    u16* __restrict__ H, float* __restrict__ out)
{
  __shared__ u16 hbuf[2][8 * 128];   // ping-pong h tiles (swizzled)
  __shared__ u16 x1tl[2][8 * 128];   // X1 ring (swizzled)
  __shared__ u16 xtl[2][8 * 128];    // X2 (gate-input x) ring (swizzled)
  __shared__ int dsh[1024];          // done[t][0..7] staged
  const int tid = threadIdx.x;
  const int w   = tid >> 6;
  const int l   = tid & 63;
  const int col = l & 15;
  const int q   = l >> 4;
  const int cl  = col & 7;
  const int n0  = blockIdx.x * 8;    // 256 blocks * 8 rows = 2048
  const int rbase = ((q & 1) << 2) + ((q >> 1) << 1);

  // resident gate-weight fragments (pre-scaled by log2e)
  b16x8 wih[4][4], whh[4][4];
  #pragma unroll
  for (int g = 0; g < 4; ++g) {
    int nt = 8 * g + w;
    #pragma unroll
    for (int c = 0; c < 4; ++c) {
      wih[g][c] = *(const b16x8*)(Wihb + (nt * 16 + col) * 128 + 8 * q + 32 * c);
      whh[g][c] = *(const b16x8*)(Whhb + (nt * 16 + col) * 128 + 8 * q + 32 * c);
    }
  }
  float gbr[4];
  #pragma unroll
  for (int g = 0; g < 4; ++g) gbr[g] = gb[(8 * g + w) * 16 + col];

  // resident MLP weight fragments for N-tile nt=w
  b16x8 w1f[2], w2f[4];
  #pragma unroll
  for (int c = 0; c < 2; ++c) w1f[c] = *(const b16x8*)(W1b + (w * 16 + col) * 64 + 8 * q + 32 * c);
  #pragma unroll
  for (int c = 0; c < 4; ++c) w2f[c] = *(const b16x8*)(W2b + (w * 16 + col) * 128 + 8 * q + 32 * c);
  const float b1r = b1v[w * 16 + col];
  const float b2r = b2v[w * 16 + col];

  // c-state
  float cc0 = c0[(n0 + rbase) * 128 + 16 * w + col];
  float cc1 = c0[(n0 + rbase + 1) * 128 + 16 * w + col];

  // stage h0 -> hbuf[0]; done -> dsh
  #pragma unroll
  for (int j = 0; j < 2; ++j) {
    int idx = tid * 2 + j;
    int row = idx >> 7, k = idx & 127;
    *(u16*)((char*)hbuf[0] + SW(row * 256 + k * 2, row)) = f2bf_bits(h0[(n0 + row) * 128 + k]);
    dsh[idx] = done[(idx >> 3) * 2048 + n0 + (idx & 7)];
  }

  // loop-invariant LDS offsets
  int offr[4];
  #pragma unroll
  for (int c = 0; c < 4; ++c) offr[c] = SW(cl * 256 + 16 * q + 64 * c, cl);
  const int wcol2 = (16 * w + col) * 2;
  const int offw0 = SW(rbase * 256 + wcol2, rbase);
  const int offw1 = SW((rbase + 1) * 256 + wcol2, rbase + 1);
  int swoff[4];                      // MLP output writes: rows m=4q+r (valid q<2), col 16w+col
  #pragma unroll
  for (int r = 0; r < 4; ++r) { int m = 4 * q + r; swoff[r] = SW(m * 256 + wcol2, m); }

  // obs addressing: lane reads row n0+cl, k = 32c+8q+2p (pairs; clamped+zeroed >=54)
  const long obl = (long)(n0 + cl) * 54;
  int koff[8]; bool kval[8];
  #pragma unroll
  for (int c = 0; c < 2; ++c)
    #pragma unroll
    for (int p = 0; p < 4; ++p) {
      int i = c * 4 + p, kk = 32 * c + 8 * q + 2 * p;
      kval[i] = (kk < 54); koff[i] = kval[i] ? kk : 0;
    }

  // H store pointers
  u16* hp0 = H + (long)(n0 + rbase) * 128 + 16 * w + col;
  u16* hp1 = H + (long)(n0 + rbase + 1) * 128 + 16 * w + col;

  // ---- MLP phase helpers ----
  auto OBSLOAD = [&](int T, float2 (&o)[8]) {
    const float* obsT = obs + (long)T * 110592 + obl;
    #pragma unroll
    for (int i = 0; i < 8; ++i) o[i] = *(const float2*)(obsT + koff[i]);
  };
  auto X1COMP = [&](const float2 (&o)[8], u16* dst) {
    b16x8 a0[2];
    #pragma unroll
    for (int c = 0; c < 2; ++c)
      #pragma unroll
      for (int p = 0; p < 4; ++p) {
        int i = c * 4 + p;
        a0[c][2 * p]     = (__bf16)(kval[i] ? o[i].x : 0.f);
        a0[c][2 * p + 1] = (__bf16)(kval[i] ? o[i].y : 0.f);
      }
    f32x4 a = fzero4();
    a = MFMA16(a0[0], w1f[0], a);
    a = MFMA16(a0[1], w1f[1], a);
    if (q < 2) {
      #pragma unroll
      for (int r = 0; r < 4; ++r)
        *(u16*)((char*)dst + swoff[r]) = f2bf_bits(fmaxf(a[r] + b1r, 0.f));
    }
  };
  auto MLPX1 = [&](int T, u16* dst) { float2 o[8]; OBSLOAD(T, o); X1COMP(o, dst); };
  auto MLPX2 = [&](const u16* src, u16* dst) {
    b16x8 a1[4];
    #pragma unroll
    for (int c = 0; c < 4; ++c) a1[c] = *(const b16x8*)((const char*)src + offr[c]);
    f32x4 a = fzero4();
    #pragma unroll
    for (int c = 0; c < 4; ++c) a = MFMA16(a1[c], w2f[c], a);
    if (q < 2) {
      #pragma unroll
      for (int r = 0; r < 4; ++r)
        *(u16*)((char*)dst + swoff[r]) = f2bf_bits(fmaxf(a[r] + b2r, 0.f));
    }
  };

  // obs prefetch registers (ping-pong, one step ahead)
  float2 oA[8], oB[8];

  // ---- prologue: X1(0,1,2), X2(0,1), accA = bias + x(0), oA = obs(3) ----
  OBSLOAD(3, oA);                          // for step 0's X1(3)
  __syncthreads();                         // h0/dsh staged
  MLPX1(0, x1tl[0]); MLPX1(1, x1tl[1]);
  __syncthreads();                         // x1 tiles visible
  MLPX2(x1tl[0], xtl[0]); MLPX2(x1tl[1], xtl[1]);
  __syncthreads();                         // x tiles visible
  MLPX1(2, x1tl[0]);
  f32x4 accA[4], accB[4];
  {
    b16x8 xa[4];
    #pragma unroll
    for (int c = 0; c < 4; ++c) xa[c] = *(const b16x8*)((const char*)xtl[0] + offr[c]);
    #pragma unroll
    for (int g = 0; g < 4; ++g) { f32x4 z; z[0]=gbr[g]; z[1]=gbr[g]; z[2]=gbr[g]; z[3]=gbr[g]; accA[g] = z; }
    #pragma unroll
    for (int g = 0; g < 4; ++g)
      #pragma unroll
      for (int c = 0; c < 4; ++c)
        accA[g] = MFMA16(xa[c], wih[g][c], accA[g]);
  }
  __syncthreads();                         // X1(2) visible; enter loop

  int dA = 0, dC0 = 0, dC1 = 0;
  float hv0 = 0.f, hv1 = 0.f;

// one fused step. OC holds obs(T+3) (loaded last step); ON gets obs(T+4) issued at top.
// X1R=X1(T+2) read by X2 phase; X1W gets X1(T+3); XTR=x(T+1) (pre-MFMA read);
// XTW gets x(T+2). AC holds bias+x(T_); AN pre-filled for T_+1.
#define LSTEP(T_, RB, WB, AC, AN, X1R, X1W, XTR, XTW, OC, ON) {                      \
    { int t4 = (T_) + 4; if (t4 > 127) t4 = 127; OBSLOAD(t4, ON); }                  \
    b16x8 ha[4];                                                                     \
    _Pragma("unroll") for (int c = 0; c < 4; ++c) {                                  \
      ha[c] = *(const b16x8*)((const char*)(RB) + offr[c]);                          \
      if (dA) ha[c] = bzero8();                                                      \
    }                                                                                \
    if (dC0) cc0 = 0.f;                                                              \
    if (dC1) cc1 = 0.f;                                                              \
    __builtin_amdgcn_s_setprio(1);                                                   \
    _Pragma("unroll") for (int g = 0; g < 4; ++g)                                    \
      _Pragma("unroll") for (int c = 0; c < 4; ++c)                                  \
        AC[g] = MFMA16(ha[c], whh[g][c], AC[g]);                                     \
    __builtin_amdgcn_s_setprio(0);                                                   \
    dA  = dsh[(T_) * 8 + cl];                                                        \
    dC0 = dsh[(T_) * 8 + rbase];                                                     \
    dC1 = dsh[(T_) * 8 + rbase + 1];                                                 \
    _Pragma("unroll") for (int g = 0; g < 4; ++g) {                                  \
      asm volatile("v_permlane32_swap_b32 %0, %1" : "+v"(AC[g][0]), "+v"(AC[g][2])); \
      asm volatile("v_permlane32_swap_b32 %0, %1" : "+v"(AC[g][1]), "+v"(AC[g][3])); \
    }                                                                                \
    cellf(AC[0][0], AC[1][0], AC[2][0], AC[3][0], cc0, hv0);                         \
    cellf(AC[0][1], AC[1][1], AC[2][1], AC[3][1], cc1, hv1);                         \
    { u32 pk;                                                                        \
      asm("v_cvt_pk_bf16_f32 %0, %1, %2" : "=v"(pk) : "v"(hv0), "v"(hv1));           \
      *(u16*)((char*)(WB) + offw0) = (u16)pk;                                        \
      *(u16*)((char*)(WB) + offw1) = (u16)(pk >> 16);                                \
      *hp0 = (u16)pk; *hp1 = (u16)(pk >> 16);                                        \
      hp0 += 262144; hp1 += 262144; }                                                \
    X1COMP(OC, X1W);                                                                 \
    MLPX2(X1R, XTW);                                                                 \
    { b16x8 xa[4];                                                                   \
      _Pragma("unroll") for (int c = 0; c < 4; ++c)                                  \
        xa[c] = *(const b16x8*)((const char*)(XTR) + offr[c]);                       \
      _Pragma("unroll") for (int g = 0; g < 4; ++g) {                                \
        f32x4 z; z[0]=gbr[g]; z[1]=gbr[g]; z[2]=gbr[g]; z[3]=gbr[g]; AN[g] = z; }    \
      __builtin_amdgcn_s_setprio(1);                                                 \
      _Pragma("unroll") for (int g = 0; g < 4; ++g)                                  \
        _Pragma("unroll") for (int c = 0; c < 4; ++c)                                \
          AN[g] = MFMA16(xa[c], wih[g][c], AN[g]);                                   \
      __builtin_amdgcn_s_setprio(0);                                                 \
    }                                                                                \
    bar_lgkm();                                                                      \
  }

  for (int tb = 0; tb < 128; tb += 2) {
    LSTEP(tb,     hbuf[0], hbuf[1], accA, accB, x1tl[0], x1tl[1], xtl[1], xtl[0], oA, oB)
    LSTEP(tb + 1, hbuf[1], hbuf[0], accB, accA, x1tl[1], x1tl[0], xtl[0], xtl[1], oB, oA)
  }
#undef LSTEP

  // final hT / cT (f32), 2 rows per lane
  {
    int k = 16 * w + col;
    out[1835008 + (n0 + rbase) * 128 + k]     = hv0;
    out[1835008 + (n0 + rbase + 1) * 128 + k] = hv1;
    out[2097152 + (n0 + rbase) * 128 + k]     = cc0;
    out[2097152 + (n0 + rbase + 1) * 128 + k] = cc1;
  }

  // drain all H stores from every wave, then compute heads from own (L2-hot) H slice
  __syncthreads();
  {
    b16x8 wh[4];
    #pragma unroll
    for (int c = 0; c < 4; ++c) wh[c] = *(const b16x8*)(Whb + col * 128 + 8 * q + 32 * c);
    const float hb = (col < 6) ? bp[col] : ((col == 6) ? bv[0] : 0.f);
    #pragma unroll
    for (int i = 0; i < 8; ++i) {
      int t0 = 16 * w + 2 * i;
      const u16* hsrc = H + ((long)(t0 + (col >> 3)) * 2048 + n0 + (col & 7)) * 128 + 8 * q;
      b16x8 a[4];
      #pragma unroll
      for (int c = 0; c < 4; ++c) a[c] = *(const b16x8*)(hsrc + 32 * c);
      f32x4 hacc = fzero4();
      #pragma unroll
      for (int c = 0; c < 4; ++c) hacc = MFMA16(a[c], wh[c], hacc);
      #pragma unroll
      for (int r = 0; r < 4; ++r) {
        int m = 4 * q + r;
        int tt = t0 + (m >> 3);
        int n = n0 + (m & 7);
        float v = hacc[r] + hb;
        if (col < 6)       out[(tt * 2048 + n) * 6 + col] = v;
        else if (col == 6) out[1572864 + tt * 2048 + n] = v;
      }
    }
  }
}

extern "C" void kernel_launch(void* const* d_in, const int* in_sizes, int n_in,
                              void* d_out, int out_size, void* d_ws, size_t ws_size,
                              hipStream_t stream) {
  const float* obs  = (const float*)d_in[0];
  const float* h0   = (const float*)d_in[1];
  const float* c0   = (const float*)d_in[2];
  const int*   done = (const int*)d_in[3];
  const float* W1   = (const float*)d_in[4];
  const float* b1   = (const float*)d_in[5];
  const float* W2   = (const float*)d_in[6];
  const float* b2   = (const float*)d_in[7];
  const float* Wih  = (const float*)d_in[8];
  const float* Whh  = (const float*)d_in[9];
  const float* bih  = (const float*)d_in[10];
  const float* bhh  = (const float*)d_in[11];
  const float* Wp   = (const float*)d_in[12];
  const float* bp   = (const float*)d_in[13];
  const float* Wv   = (const float*)d_in[14];
  const float* bv   = (const float*)d_in[15];

  char* ws = (char*)d_ws;
  u16*   H    = (u16*)(ws);                                      // 67108864 B
  u16*   W1b  = (u16*)(ws + 67108864);                           // 16384 B
  u16*   W2b  = (u16*)(ws + 67108864 + 16384);                   // 32768 B
  u16*   Wihb = (u16*)(ws + 67108864 + 16384 + 32768);           // 131072 B
  u16*   Whhb = (u16*)(ws + 67108864 + 16384 + 32768 + 131072);  // 131072 B
  u16*   Whb  = (u16*)(ws + 67108864 + 16384 + 32768 + 262144);  // 4096 B
  float* gbp  = (float*)(ws + 67108864 + 16384 + 32768 + 262144 + 4096);
  float* out  = (float*)d_out;

  hipLaunchKernelGGL(prep_kernel, dim3(256), dim3(256), 0, stream,
                     W1, W2, Wih, Whh, Wp, Wv, bih, bhh, W1b, W2b, Wihb, Whhb, Whb, gbp);
  hipLaunchKernelGGL(lstm_fused_kernel, dim3(256), dim3(512), 0, stream,
                     obs, h0, c0, done, W1b, W2b, Wihb, Whhb, Whb, gbp, b1, b2, bp, bv, H, out);
}

// Round 12
// 243.094 us; speedup vs baseline: 1.7409x; 1.7361x over previous
//
#include <hip/hip_runtime.h>

typedef __attribute__((ext_vector_type(8))) __bf16 b16x8;
typedef __attribute__((ext_vector_type(4))) float f32x4;
typedef unsigned short u16;
typedef unsigned int u32;

#define MFMA16(a, b, c) __builtin_amdgcn_mfma_f32_16x16x32_bf16((a), (b), (c), 0, 0, 0)
// XOR swizzle: spread 16B slots across banks for row-major bf16 tiles w/ 256B row stride
#define SW(byteoff, row) ((byteoff) ^ (((row) & 7) << 4))
#define LOG2E 1.4426950408889634f

__device__ __forceinline__ u16 f2bf_bits(float f) {
  union { float f; unsigned u; } v; v.f = f;
  unsigned r = (v.u + 0x7FFFu + ((v.u >> 16) & 1u)) >> 16;
  return (u16)r;
}
__device__ __forceinline__ float rcp_f(float x) { float r; asm("v_rcp_f32 %0, %1" : "=v"(r) : "v"(x)); return r; }
__device__ __forceinline__ float exp2_f(float x) { float r; asm("v_exp_f32 %0, %1" : "=v"(r) : "v"(x)); return r; }
__device__ __forceinline__ f32x4 fzero4() { f32x4 z; z[0]=0.f; z[1]=0.f; z[2]=0.f; z[3]=0.f; return z; }
__device__ __forceinline__ b16x8 bzero8() {
  b16x8 z;
  #pragma unroll
  for (int j = 0; j < 8; ++j) z[j] = (__bf16)0.f;
  return z;
}
// barrier that drains only LDS (no vmcnt drain): loads/stores fly across
__device__ __forceinline__ void bar_lgkm() {
  asm volatile("s_waitcnt lgkmcnt(0)\n\ts_barrier" ::: "memory");
}
// LSTM cell elementwise; gate pre-activations (incl. bias) already scaled by log2e
__device__ __forceinline__ void cellf(float gi, float gf, float gg, float go,
                                      float& cc, float& hv) {
  float si = rcp_f(1.f + exp2_f(-gi));
  float sf = rcp_f(1.f + exp2_f(-gf));
  float tg = 1.f - 2.f * rcp_f(1.f + exp2_f(gg + gg));
  float cn = sf * cc + si * tg;
  float so = rcp_f(1.f + exp2_f(-go));
  float tc = 1.f - 2.f * rcp_f(1.f + exp2_f(2.8853900817779268f * cn));
  cc = cn; hv = so * tc;
}

// ---------------- prep: weights -> bf16 (gate weights pre-scaled by log2e) ----------------
__global__ __launch_bounds__(256) void prep_kernel(
    const float* __restrict__ W1, const float* __restrict__ W2,
    const float* __restrict__ Wih, const float* __restrict__ Whh,
    const float* __restrict__ Wp, const float* __restrict__ Wv,
    const float* __restrict__ bih, const float* __restrict__ bhh,
    u16* __restrict__ W1b, u16* __restrict__ W2b, u16* __restrict__ Wihb,
    u16* __restrict__ Whhb, u16* __restrict__ Whb, float* __restrict__ gbp)
{
  int i = blockIdx.x * 256 + threadIdx.x;   // grid 256*256 = 65536
  if (i < 8192) {                            // W1 padded (128 x 64), K 54->64
    int r = i >> 6, k = i & 63;
    W1b[i] = f2bf_bits(k < 54 ? W1[r * 54 + k] : 0.f);
  }
  if (i < 16384) W2b[i] = f2bf_bits(W2[i]);  // 128x128
  Wihb[i] = f2bf_bits(LOG2E * Wih[i]);       // 512x128, pre-scaled
  Whhb[i] = f2bf_bits(LOG2E * Whh[i]);       // 512x128, pre-scaled
  if (i < 2048) {                            // head: rows 0-5 Wp, 6 Wv, 7-15 zero (16x128)
    int r = i >> 7, k = i & 127;
    float v = (r < 6) ? Wp[r * 128 + k] : ((r == 6) ? Wv[k] : 0.f);
    Whb[i] = f2bf_bits(v);                   // NOT scaled
  }
  if (i < 512) gbp[i] = LOG2E * (bih[i] + bhh[i]);
}

// ---------------- fused MLP + LSTM recurrence + heads ----------------
// 256 blocks x 8 batch rows, 512 threads (8 waves); wave w owns gate cols [16w,16w+16)
// AND MLP N-tile nt=w. Per step t: obs(t+3) loads ISSUED at the top of the step and
// CONSUMED (X1COMP) at the bottom -> the whole step body hides the HBM latency, with
// no cross-step register lifetime (r10/r11 showed the 256-reg unified cap forbids
// cross-step obs buffers). X2(t+2) from the X1 ring; gate-input x from LDS; x-MFMAs
// for t+1 pre-issued before the barrier. h_t -> LDS ring + global H (never read
// in-loop -> no vmcnt drain); heads after the loop from L2-hot H.
__global__ __launch_bounds__(512) void lstm_fused_kernel(
    const float* __restrict__ obs, const float* __restrict__ h0, const float* __restrict__ c0,
    const int* __restrict__ done,
    const u16* __restrict__ W1b, const u16* __restrict__ W2b,
    const u16* __restrict__ Wihb, const u16* __restrict__ Whhb, const u16* __restrict__ Whb,
    const float* __restrict__ gb, const float* __restrict__ b1v, const float* __restrict__ b2v,
    const float* __restrict__ bp, const float* __restrict__ bv,
    u16* __restrict__ H, float* __restrict__ out)
{
  __shared__ u16 hbuf[2][8 * 128];   // ping-pong h tiles (swizzled)
  __shared__ u16 x1tl[2][8 * 128];   // X1 ring (swizzled)
  __shared__ u16 xtl[2][8 * 128];    // X2 (gate-input x) ring (swizzled)
  __shared__ int dsh[1024];          // done[t][0..7] staged
  const int tid = threadIdx.x;
  const int w   = tid >> 6;
  const int l   = tid & 63;
  const int col = l & 15;
  const int q   = l >> 4;
  const int cl  = col & 7;
  const int n0  = blockIdx.x * 8;    // 256 blocks * 8 rows = 2048
  const int rbase = ((q & 1) << 2) + ((q >> 1) << 1);

  // resident gate-weight fragments (pre-scaled by log2e)
  b16x8 wih[4][4], whh[4][4];
  #pragma unroll
  for (int g = 0; g < 4; ++g) {
    int nt = 8 * g + w;
    #pragma unroll
    for (int c = 0; c < 4; ++c) {
      wih[g][c] = *(const b16x8*)(Wihb + (nt * 16 + col) * 128 + 8 * q + 32 * c);
      whh[g][c] = *(const b16x8*)(Whhb + (nt * 16 + col) * 128 + 8 * q + 32 * c);
    }
  }
  float gbr[4];
  #pragma unroll
  for (int g = 0; g < 4; ++g) gbr[g] = gb[(8 * g + w) * 16 + col];

  // resident MLP weight fragments for N-tile nt=w
  b16x8 w1f[2], w2f[4];
  #pragma unroll
  for (int c = 0; c < 2; ++c) w1f[c] = *(const b16x8*)(W1b + (w * 16 + col) * 64 + 8 * q + 32 * c);
  #pragma unroll
  for (int c = 0; c < 4; ++c) w2f[c] = *(const b16x8*)(W2b + (w * 16 + col) * 128 + 8 * q + 32 * c);
  const float b1r = b1v[w * 16 + col];
  const float b2r = b2v[w * 16 + col];

  // c-state
  float cc0 = c0[(n0 + rbase) * 128 + 16 * w + col];
  float cc1 = c0[(n0 + rbase + 1) * 128 + 16 * w + col];

  // stage h0 -> hbuf[0]; done -> dsh
  #pragma unroll
  for (int j = 0; j < 2; ++j) {
    int idx = tid * 2 + j;
    int row = idx >> 7, k = idx & 127;
    *(u16*)((char*)hbuf[0] + SW(row * 256 + k * 2, row)) = f2bf_bits(h0[(n0 + row) * 128 + k]);
    dsh[idx] = done[(idx >> 3) * 2048 + n0 + (idx & 7)];
  }

  // loop-invariant LDS offsets
  int offr[4];
  #pragma unroll
  for (int c = 0; c < 4; ++c) offr[c] = SW(cl * 256 + 16 * q + 64 * c, cl);
  const int wcol2 = (16 * w + col) * 2;
  const int offw0 = SW(rbase * 256 + wcol2, rbase);
  const int offw1 = SW((rbase + 1) * 256 + wcol2, rbase + 1);
  int swoff[4];                      // MLP output writes: rows m=4q+r (valid q<2), col 16w+col
  #pragma unroll
  for (int r = 0; r < 4; ++r) { int m = 4 * q + r; swoff[r] = SW(m * 256 + wcol2, m); }

  // obs addressing: lane reads row n0+cl, k = 32c+8q+2p (pairs; clamped+zeroed >=54)
  const long obl = (long)(n0 + cl) * 54;
  int koff[8]; bool kval[8];
  #pragma unroll
  for (int c = 0; c < 2; ++c)
    #pragma unroll
    for (int p = 0; p < 4; ++p) {
      int i = c * 4 + p, kk = 32 * c + 8 * q + 2 * p;
      kval[i] = (kk < 54); koff[i] = kval[i] ? kk : 0;
    }

  // H store pointers
  u16* hp0 = H + (long)(n0 + rbase) * 128 + 16 * w + col;
  u16* hp1 = H + (long)(n0 + rbase + 1) * 128 + 16 * w + col;

  // ---- MLP phase helpers ----
  auto OBSLOAD = [&](int T, float2 (&o)[8]) {
    const float* obsT = obs + (long)T * 110592 + obl;
    #pragma unroll
    for (int i = 0; i < 8; ++i) o[i] = *(const float2*)(obsT + koff[i]);
  };
  auto X1COMP = [&](const float2 (&o)[8], u16* dst) {
    b16x8 a0[2];
    #pragma unroll
    for (int c = 0; c < 2; ++c)
      #pragma unroll
      for (int p = 0; p < 4; ++p) {
        int i = c * 4 + p;
        a0[c][2 * p]     = (__bf16)(kval[i] ? o[i].x : 0.f);
        a0[c][2 * p + 1] = (__bf16)(kval[i] ? o[i].y : 0.f);
      }
    f32x4 a = fzero4();
    a = MFMA16(a0[0], w1f[0], a);
    a = MFMA16(a0[1], w1f[1], a);
    if (q < 2) {
      #pragma unroll
      for (int r = 0; r < 4; ++r)
        *(u16*)((char*)dst + swoff[r]) = f2bf_bits(fmaxf(a[r] + b1r, 0.f));
    }
  };
  auto MLPX1 = [&](int T, u16* dst) { float2 o[8]; OBSLOAD(T, o); X1COMP(o, dst); };
  auto MLPX2 = [&](const u16* src, u16* dst) {
    b16x8 a1[4];
    #pragma unroll
    for (int c = 0; c < 4; ++c) a1[c] = *(const b16x8*)((const char*)src + offr[c]);
    f32x4 a = fzero4();
    #pragma unroll
    for (int c = 0; c < 4; ++c) a = MFMA16(a1[c], w2f[c], a);
    if (q < 2) {
      #pragma unroll
      for (int r = 0; r < 4; ++r)
        *(u16*)((char*)dst + swoff[r]) = f2bf_bits(fmaxf(a[r] + b2r, 0.f));
    }
  };

  // ---- prologue: X1(0,1,2), X2(0,1), accA = bias + x(0) ----
  __syncthreads();                         // h0/dsh staged
  MLPX1(0, x1tl[0]); MLPX1(1, x1tl[1]);
  __syncthreads();                         // x1 tiles visible
  MLPX2(x1tl[0], xtl[0]); MLPX2(x1tl[1], xtl[1]);
  __syncthreads();                         // x tiles visible
  MLPX1(2, x1tl[0]);
  f32x4 accA[4], accB[4];
  {
    b16x8 xa[4];
    #pragma unroll
    for (int c = 0; c < 4; ++c) xa[c] = *(const b16x8*)((const char*)xtl[0] + offr[c]);
    #pragma unroll
    for (int g = 0; g < 4; ++g) { f32x4 z; z[0]=gbr[g]; z[1]=gbr[g]; z[2]=gbr[g]; z[3]=gbr[g]; accA[g] = z; }
    #pragma unroll
    for (int g = 0; g < 4; ++g)
      #pragma unroll
      for (int c = 0; c < 4; ++c)
        accA[g] = MFMA16(xa[c], wih[g][c], accA[g]);
  }
  __syncthreads();                         // X1(2) visible; enter loop

  int dA = 0, dC0 = 0, dC1 = 0;
  float hv0 = 0.f, hv1 = 0.f;

// one fused step. obs(T+3) loads issued FIRST (o_), consumed LAST (X1COMP) -> the
// step body hides the latency; o_ lifetime stays within the step (no reg-cap blowout).
// X1R=X1(T+2) read by X2 phase; X1W gets X1(T+3); XTR=x(T+1) (pre-MFMA read);
// XTW gets x(T+2). AC holds bias+x(T_); AN pre-filled for T_+1.
#define LSTEP(T_, RB, WB, AC, AN, X1R, X1W, XTR, XTW) {                              \
    float2 o_[8];                                                                    \
    { int t3 = (T_) + 3; if (t3 > 127) t3 = 127; OBSLOAD(t3, o_); }                  \
    b16x8 ha[4];                                                                     \
    _Pragma("unroll") for (int c = 0; c < 4; ++c) {                                  \
      ha[c] = *(const b16x8*)((const char*)(RB) + offr[c]);                          \
      if (dA) ha[c] = bzero8();                                                      \
    }                                                                                \
    if (dC0) cc0 = 0.f;                                                              \
    if (dC1) cc1 = 0.f;                                                              \
    __builtin_amdgcn_s_setprio(1);                                                   \
    _Pragma("unroll") for (int g = 0; g < 4; ++g)                                    \
      _Pragma("unroll") for (int c = 0; c < 4; ++c)                                  \
        AC[g] = MFMA16(ha[c], whh[g][c], AC[g]);                                     \
    __builtin_amdgcn_s_setprio(0);                                                   \
    dA  = dsh[(T_) * 8 + cl];                                                        \
    dC0 = dsh[(T_) * 8 + rbase];                                                     \
    dC1 = dsh[(T_) * 8 + rbase + 1];                                                 \
    _Pragma("unroll") for (int g = 0; g < 4; ++g) {                                  \
      asm volatile("v_permlane32_swap_b32 %0, %1" : "+v"(AC[g][0]), "+v"(AC[g][2])); \
      asm volatile("v_permlane32_swap_b32 %0, %1" : "+v"(AC[g][1]), "+v"(AC[g][3])); \
    }                                                                                \
    cellf(AC[0][0], AC[1][0], AC[2][0], AC[3][0], cc0, hv0);                         \
    cellf(AC[0][1], AC[1][1], AC[2][1], AC[3][1], cc1, hv1);                         \
    { u32 pk;                                                                        \
      asm("v_cvt_pk_bf16_f32 %0, %1, %2" : "=v"(pk) : "v"(hv0), "v"(hv1));           \
      *(u16*)((char*)(WB) + offw0) = (u16)pk;                                        \
      *(u16*)((char*)(WB) + offw1) = (u16)(pk >> 16);                                \
      *hp0 = (u16)pk; *hp1 = (u16)(pk >> 16);                                        \
      hp0 += 262144; hp1 += 262144; }                                                \
    MLPX2(X1R, XTW);                                                                 \
    { b16x8 xa[4];                                                                   \
      _Pragma("unroll") for (int c = 0; c < 4; ++c)                                  \
        xa[c] = *(const b16x8*)((const char*)(XTR) + offr[c]);                       \
      _Pragma("unroll") for (int g = 0; g < 4; ++g) {                                \
        f32x4 z; z[0]=gbr[g]; z[1]=gbr[g]; z[2]=gbr[g]; z[3]=gbr[g]; AN[g] = z; }    \
      __builtin_amdgcn_s_setprio(1);                                                 \
      _Pragma("unroll") for (int g = 0; g < 4; ++g)                                  \
        _Pragma("unroll") for (int c = 0; c < 4; ++c)                                \
          AN[g] = MFMA16(xa[c], wih[g][c], AN[g]);                                   \
      __builtin_amdgcn_s_setprio(0);                                                 \
    }                                                                                \
    X1COMP(o_, X1W);                                                                 \
    bar_lgkm();                                                                      \
  }

  for (int tb = 0; tb < 128; tb += 2) {
    LSTEP(tb,     hbuf[0], hbuf[1], accA, accB, x1tl[0], x1tl[1], xtl[1], xtl[0])
    LSTEP(tb + 1, hbuf[1], hbuf[0], accB, accA, x1tl[1], x1tl[0], xtl[0], xtl[1])
  }
#undef LSTEP

  // final hT / cT (f32), 2 rows per lane
  {
    int k = 16 * w + col;
    out[1835008 + (n0 + rbase) * 128 + k]     = hv0;
    out[1835008 + (n0 + rbase + 1) * 128 + k] = hv1;
    out[2097152 + (n0 + rbase) * 128 + k]     = cc0;
    out[2097152 + (n0 + rbase + 1) * 128 + k] = cc1;
  }

  // drain all H stores from every wave, then compute heads from own (L2-hot) H slice
  __syncthreads();
  {
    b16x8 wh[4];
    #pragma unroll
    for (int c = 0; c < 4; ++c) wh[c] = *(const b16x8*)(Whb + col * 128 + 8 * q + 32 * c);
    const float hb = (col < 6) ? bp[col] : ((col == 6) ? bv[0] : 0.f);
    #pragma unroll
    for (int i = 0; i < 8; ++i) {
      int t0 = 16 * w + 2 * i;
      const u16* hsrc = H + ((long)(t0 + (col >> 3)) * 2048 + n0 + (col & 7)) * 128 + 8 * q;
      b16x8 a[4];
      #pragma unroll
      for (int c = 0; c < 4; ++c) a[c] = *(const b16x8*)(hsrc + 32 * c);
      f32x4 hacc = fzero4();
      #pragma unroll
      for (int c = 0; c < 4; ++c) hacc = MFMA16(a[c], wh[c], hacc);
      #pragma unroll
      for (int r = 0; r < 4; ++r) {
        int m = 4 * q + r;
        int tt = t0 + (m >> 3);
        int n = n0 + (m & 7);
        float v = hacc[r] + hb;
        if (col < 6)       out[(tt * 2048 + n) * 6 + col] = v;
        else if (col == 6) out[1572864 + tt * 2048 + n] = v;
      }
    }
  }
}

extern "C" void kernel_launch(void* const* d_in, const int* in_sizes, int n_in,
                              void* d_out, int out_size, void* d_ws, size_t ws_size,
                              hipStream_t stream) {
  const float* obs  = (const float*)d_in[0];
  const float* h0   = (const float*)d_in[1];
  const float* c0   = (const float*)d_in[2];
  const int*   done = (const int*)d_in[3];
  const float* W1   = (const float*)d_in[4];
  const float* b1   = (const float*)d_in[5];
  const float* W2   = (const float*)d_in[6];
  const float* b2   = (const float*)d_in[7];
  const float* Wih  = (const float*)d_in[8];
  const float* Whh  = (const float*)d_in[9];
  const float* bih  = (const float*)d_in[10];
  const float* bhh  = (const float*)d_in[11];
  const float* Wp   = (const float*)d_in[12];
  const float* bp   = (const float*)d_in[13];
  const float* Wv   = (const float*)d_in[14];
  const float* bv   = (const float*)d_in[15];

  char* ws = (char*)d_ws;
  u16*   H    = (u16*)(ws);                                      // 67108864 B
  u16*   W1b  = (u16*)(ws + 67108864);                           // 16384 B
  u16*   W2b  = (u16*)(ws + 67108864 + 16384);                   // 32768 B
  u16*   Wihb = (u16*)(ws + 67108864 + 16384 + 32768);           // 131072 B
  u16*   Whhb = (u16*)(ws + 67108864 + 16384 + 32768 + 131072);  // 131072 B
  u16*   Whb  = (u16*)(ws + 67108864 + 16384 + 32768 + 262144);  // 4096 B
  float* gbp  = (float*)(ws + 67108864 + 16384 + 32768 + 262144 + 4096);
  float* out  = (float*)d_out;

  hipLaunchKernelGGL(prep_kernel, dim3(256), dim3(256), 0, stream,
                     W1, W2, Wih, Whh, Wp, Wv, bih, bhh, W1b, W2b, Wihb, Whhb, Whb, gbp);
  hipLaunchKernelGGL(lstm_fused_kernel, dim3(256), dim3(512), 0, stream,
                     obs, h0, c0, done, W1b, W2b, Wihb, Whhb, Whb, gbp, b1, b2, bp, bv, H, out);
}

// Round 13
// 238.617 us; speedup vs baseline: 1.7736x; 1.0188x over previous
//
#include <hip/hip_runtime.h>

typedef __attribute__((ext_vector_type(8))) __bf16 b16x8;
typedef __attribute__((ext_vector_type(4))) float f32x4;
typedef unsigned short u16;
typedef unsigned int u32;

#define MFMA16(a, b, c) __builtin_amdgcn_mfma_f32_16x16x32_bf16((a), (b), (c), 0, 0, 0)
// XOR swizzle: spread 16B slots across banks for row-major bf16 tiles w/ 256B row stride
#define SW(byteoff, row) ((byteoff) ^ (((row) & 7) << 4))
#define LOG2E 1.4426950408889634f

__device__ __forceinline__ u16 f2bf_bits(float f) {
  union { float f; unsigned u; } v; v.f = f;
  unsigned r = (v.u + 0x7FFFu + ((v.u >> 16) & 1u)) >> 16;
  return (u16)r;
}
__device__ __forceinline__ float rcp_f(float x) { float r; asm("v_rcp_f32 %0, %1" : "=v"(r) : "v"(x)); return r; }
__device__ __forceinline__ float exp2_f(float x) { float r; asm("v_exp_f32 %0, %1" : "=v"(r) : "v"(x)); return r; }
__device__ __forceinline__ f32x4 fzero4() { f32x4 z; z[0]=0.f; z[1]=0.f; z[2]=0.f; z[3]=0.f; return z; }
__device__ __forceinline__ b16x8 bzero8() {
  b16x8 z;
  #pragma unroll
  for (int j = 0; j < 8; ++j) z[j] = (__bf16)0.f;
  return z;
}
// barrier that drains only LDS (no vmcnt drain): loads/stores fly across
__device__ __forceinline__ void bar_lgkm() {
  asm volatile("s_waitcnt lgkmcnt(0)\n\ts_barrier" ::: "memory");
}
// LSTM cell elementwise; gate pre-activations (incl. bias) already scaled by log2e
__device__ __forceinline__ void cellf(float gi, float gf, float gg, float go,
                                      float& cc, float& hv) {
  float si = rcp_f(1.f + exp2_f(-gi));
  float sf = rcp_f(1.f + exp2_f(-gf));
  float tg = 1.f - 2.f * rcp_f(1.f + exp2_f(gg + gg));
  float cn = sf * cc + si * tg;
  float so = rcp_f(1.f + exp2_f(-go));
  float tc = 1.f - 2.f * rcp_f(1.f + exp2_f(2.8853900817779268f * cn));
  cc = cn; hv = so * tc;
}

// ---------------- prep: weights -> bf16 (gate weights pre-scaled by log2e) ----------------
__global__ __launch_bounds__(256) void prep_kernel(
    const float* __restrict__ W1, const float* __restrict__ W2,
    const float* __restrict__ Wih, const float* __restrict__ Whh,
    const float* __restrict__ Wp, const float* __restrict__ Wv,
    const float* __restrict__ bih, const float* __restrict__ bhh,
    u16* __restrict__ W1b, u16* __restrict__ W2b, u16* __restrict__ Wihb,
    u16* __restrict__ Whhb, u16* __restrict__ Whb, float* __restrict__ gbp)
{
  int i = blockIdx.x * 256 + threadIdx.x;   // grid 256*256 = 65536
  if (i < 8192) {                            // W1 padded (128 x 64), K 54->64
    int r = i >> 6, k = i & 63;
    W1b[i] = f2bf_bits(k < 54 ? W1[r * 54 + k] : 0.f);
  }
  if (i < 16384) W2b[i] = f2bf_bits(W2[i]);  // 128x128
  Wihb[i] = f2bf_bits(LOG2E * Wih[i]);       // 512x128, pre-scaled
  Whhb[i] = f2bf_bits(LOG2E * Whh[i]);       // 512x128, pre-scaled
  if (i < 2048) {                            // head: rows 0-5 Wp, 6 Wv, 7-15 zero (16x128)
    int r = i >> 7, k = i & 127;
    float v = (r < 6) ? Wp[r * 128 + k] : ((r == 6) ? Wv[k] : 0.f);
    Whb[i] = f2bf_bits(v);                   // NOT scaled
  }
  if (i < 512) gbp[i] = LOG2E * (bih[i] + bhh[i]);
}

// ---------------- fused MLP + LSTM recurrence + heads ----------------
// 256 blocks x 8 batch rows, 512 threads (8 waves); wave w owns gate cols [16w,16w+16)
// AND MLP N-tile nt=w. MLP runs PAIRED (2 timesteps per M=16 tile: A-row=col, rows
// 0-7 = t, 8-15 = t+1) on EVEN steps only -> half the MLP MFMAs/obs-loads/cvt-VALU
// vs per-step, and all 64 lanes productive. Even step T: obs pair (T+4,T+5) loaded
// (issued top, consumed bottom), X1 pair (T+4,T+5) -> x1p ring, X2 pair (T+2,T+3)
// -> 4-slot x ring. xa fragment reads hoisted right after the h-MFMA cluster (cell
// section covers their latency; xa reuses ha's dead regs -> no pressure growth).
// h_t -> LDS ring + global H (never read in-loop -> no vmcnt drain); heads after.
__global__ __launch_bounds__(512) void lstm_fused_kernel(
    const float* __restrict__ obs, const float* __restrict__ h0, const float* __restrict__ c0,
    const int* __restrict__ done,
    const u16* __restrict__ W1b, const u16* __restrict__ W2b,
    const u16* __restrict__ Wihb, const u16* __restrict__ Whhb, const u16* __restrict__ Whb,
    const float* __restrict__ gb, const float* __restrict__ b1v, const float* __restrict__ b2v,
    const float* __restrict__ bp, const float* __restrict__ bv,
    u16* __restrict__ H, float* __restrict__ out)
{
  __shared__ u16 hbuf[2][8 * 128];   // ping-pong h tiles (swizzled)
  __shared__ u16 x1p[2][16 * 128];   // X1 PAIR ring (2 timesteps per buffer, swizzled)
  __shared__ u16 xtl[4][8 * 128];    // gate-input x ring, slot = t & 3 (swizzled)
  __shared__ int dsh[1024];          // done[t][0..7] staged
  const int tid = threadIdx.x;
  const int w   = tid >> 6;
  const int l   = tid & 63;
  const int col = l & 15;
  const int q   = l >> 4;
  const int cl  = col & 7;
  const int n0  = blockIdx.x * 8;    // 256 blocks * 8 rows = 2048
  const int rbase = ((q & 1) << 2) + ((q >> 1) << 1);

  // resident gate-weight fragments (pre-scaled by log2e)
  b16x8 wih[4][4], whh[4][4];
  #pragma unroll
  for (int g = 0; g < 4; ++g) {
    int nt = 8 * g + w;
    #pragma unroll
    for (int c = 0; c < 4; ++c) {
      wih[g][c] = *(const b16x8*)(Wihb + (nt * 16 + col) * 128 + 8 * q + 32 * c);
      whh[g][c] = *(const b16x8*)(Whhb + (nt * 16 + col) * 128 + 8 * q + 32 * c);
    }
  }
  float gbr[4];
  #pragma unroll
  for (int g = 0; g < 4; ++g) gbr[g] = gb[(8 * g + w) * 16 + col];

  // resident MLP weight fragments for N-tile nt=w
  b16x8 w1f[2], w2f[4];
  #pragma unroll
  for (int c = 0; c < 2; ++c) w1f[c] = *(const b16x8*)(W1b + (w * 16 + col) * 64 + 8 * q + 32 * c);
  #pragma unroll
  for (int c = 0; c < 4; ++c) w2f[c] = *(const b16x8*)(W2b + (w * 16 + col) * 128 + 8 * q + 32 * c);
  const float b1r = b1v[w * 16 + col];
  const float b2r = b2v[w * 16 + col];

  // c-state
  float cc0 = c0[(n0 + rbase) * 128 + 16 * w + col];
  float cc1 = c0[(n0 + rbase + 1) * 128 + 16 * w + col];

  // stage h0 -> hbuf[0]; done -> dsh
  #pragma unroll
  for (int j = 0; j < 2; ++j) {
    int idx = tid * 2 + j;
    int row = idx >> 7, k = idx & 127;
    *(u16*)((char*)hbuf[0] + SW(row * 256 + k * 2, row)) = f2bf_bits(h0[(n0 + row) * 128 + k]);
    dsh[idx] = done[(idx >> 3) * 2048 + n0 + (idx & 7)];
  }

  // loop-invariant LDS offsets
  int offr[4];                       // 8-row tiles (h, x): row = cl
  #pragma unroll
  for (int c = 0; c < 4; ++c) offr[c] = SW(cl * 256 + 16 * q + 64 * c, cl);
  int offp[4];                       // 16-row pair tiles (x1p): row = col
  #pragma unroll
  for (int c = 0; c < 4; ++c) offp[c] = SW(col * 256 + 16 * q + 64 * c, col);
  const int wcol2 = (16 * w + col) * 2;
  const int offw0 = SW(rbase * 256 + wcol2, rbase);
  const int offw1 = SW((rbase + 1) * 256 + wcol2, rbase + 1);
  int swoff[4];                      // X1-pair writes: rows m=4q+r (0..15), all lanes
  #pragma unroll
  for (int r = 0; r < 4; ++r) { int m = 4 * q + r; swoff[r] = SW(m * 256 + wcol2, m); }
  int swx[4];                        // X2-pair writes: row (m&7) in x-tile
  #pragma unroll
  for (int r = 0; r < 4; ++r) { int mm = (4 * q + r) & 7; swx[r] = SW(mm * 256 + wcol2, mm); }

  // obs addressing: lane reads batch row n0+cl, k = 32c+8q+2p (pairs; zeroed >=54)
  const long obl = (long)(n0 + cl) * 54;
  int koff[8]; bool kval[8];
  #pragma unroll
  for (int c = 0; c < 2; ++c)
    #pragma unroll
    for (int p = 0; p < 4; ++p) {
      int i = c * 4 + p, kk = 32 * c + 8 * q + 2 * p;
      kval[i] = (kk < 54); koff[i] = kval[i] ? kk : 0;
    }

  // H store pointers
  u16* hp0 = H + (long)(n0 + rbase) * 128 + 16 * w + col;
  u16* hp1 = H + (long)(n0 + rbase + 1) * 128 + 16 * w + col;

  // ---- MLP helpers (pair form) ----
  auto OBSROW = [&](int trow, float2 (&o)[8]) {   // per-lane timestep row
    const float* obsT = obs + (long)trow * 110592 + obl;
    #pragma unroll
    for (int i = 0; i < 8; ++i) o[i] = *(const float2*)(obsT + koff[i]);
  };
  auto X1CP = [&](const float2 (&o)[8], u16* dst) {  // pair X1: all lanes write
    b16x8 a0[2];
    #pragma unroll
    for (int c = 0; c < 2; ++c)
      #pragma unroll
      for (int p = 0; p < 4; ++p) {
        int i = c * 4 + p;
        a0[c][2 * p]     = (__bf16)(kval[i] ? o[i].x : 0.f);
        a0[c][2 * p + 1] = (__bf16)(kval[i] ? o[i].y : 0.f);
      }
    f32x4 a = fzero4();
    a = MFMA16(a0[0], w1f[0], a);
    a = MFMA16(a0[1], w1f[1], a);
    #pragma unroll
    for (int r = 0; r < 4; ++r)
      *(u16*)((char*)dst + swoff[r]) = f2bf_bits(fmaxf(a[r] + b1r, 0.f));
  };
  auto X2P = [&](const u16* src, int sbase) {     // pair X2: rows 0-7 -> slot sbase, 8-15 -> sbase+1
    b16x8 a1[4];
    #pragma unroll
    for (int c = 0; c < 4; ++c) a1[c] = *(const b16x8*)((const char*)src + offp[c]);
    f32x4 a = fzero4();
    #pragma unroll
    for (int c = 0; c < 4; ++c) a = MFMA16(a1[c], w2f[c], a);
    u16* dst = xtl[sbase + (q >> 1)];
    #pragma unroll
    for (int r = 0; r < 4; ++r)
      *(u16*)((char*)dst + swx[r]) = f2bf_bits(fmaxf(a[r] + b2r, 0.f));
  };

  // ---- prologue ----
  __syncthreads();                         // h0/dsh staged
  { float2 o[8]; OBSROW(0 + (col >> 3), o); X1CP(o, x1p[0]); }   // X1 pair (0,1)
  { float2 o[8]; OBSROW(2 + (col >> 3), o); X1CP(o, x1p[1]); }   // X1 pair (2,3)
  __syncthreads();
  X2P(x1p[0], 0);                          // x(0)->slot0, x(1)->slot1
  __syncthreads();
  f32x4 accA[4], accB[4];
  {
    b16x8 xa[4];
    #pragma unroll
    for (int c = 0; c < 4; ++c) xa[c] = *(const b16x8*)((const char*)xtl[0] + offr[c]);
    #pragma unroll
    for (int g = 0; g < 4; ++g) { f32x4 z; z[0]=gbr[g]; z[1]=gbr[g]; z[2]=gbr[g]; z[3]=gbr[g]; accA[g] = z; }
    #pragma unroll
    for (int g = 0; g < 4; ++g)
      #pragma unroll
      for (int c = 0; c < 4; ++c)
        accA[g] = MFMA16(xa[c], wih[g][c], accA[g]);
  }

  int dA = 0, dC0 = 0, dC1 = 0;
  float hv0 = 0.f, hv1 = 0.f;

// shared step core: h-MFMA -> xa hoist -> cell -> h write. XSLOT: x(T+1) ring slot.
#define LCORE(T_, RB, WB, AC, AN, XSLOT, XA_)                                        \
    b16x8 ha[4];                                                                     \
    _Pragma("unroll") for (int c = 0; c < 4; ++c) {                                  \
      ha[c] = *(const b16x8*)((const char*)(RB) + offr[c]);                          \
      if (dA) ha[c] = bzero8();                                                      \
    }                                                                                \
    if (dC0) cc0 = 0.f;                                                              \
    if (dC1) cc1 = 0.f;                                                              \
    __builtin_amdgcn_s_setprio(1);                                                   \
    _Pragma("unroll") for (int g = 0; g < 4; ++g)                                    \
      _Pragma("unroll") for (int c = 0; c < 4; ++c)                                  \
        AC[g] = MFMA16(ha[c], whh[g][c], AC[g]);                                     \
    __builtin_amdgcn_s_setprio(0);                                                   \
    b16x8 XA_[4];                                                                    \
    _Pragma("unroll") for (int c = 0; c < 4; ++c)                                    \
      XA_[c] = *(const b16x8*)((const char*)xtl[XSLOT] + offr[c]);                   \
    dA  = dsh[(T_) * 8 + cl];                                                        \
    dC0 = dsh[(T_) * 8 + rbase];                                                     \
    dC1 = dsh[(T_) * 8 + rbase + 1];                                                 \
    _Pragma("unroll") for (int g = 0; g < 4; ++g) {                                  \
      asm volatile("v_permlane32_swap_b32 %0, %1" : "+v"(AC[g][0]), "+v"(AC[g][2])); \
      asm volatile("v_permlane32_swap_b32 %0, %1" : "+v"(AC[g][1]), "+v"(AC[g][3])); \
    }                                                                                \
    cellf(AC[0][0], AC[1][0], AC[2][0], AC[3][0], cc0, hv0);                         \
    cellf(AC[0][1], AC[1][1], AC[2][1], AC[3][1], cc1, hv1);                         \
    { u32 pk;                                                                        \
      asm("v_cvt_pk_bf16_f32 %0, %1, %2" : "=v"(pk) : "v"(hv0), "v"(hv1));           \
      *(u16*)((char*)(WB) + offw0) = (u16)pk;                                        \
      *(u16*)((char*)(WB) + offw1) = (u16)(pk >> 16);                                \
      *hp0 = (u16)pk; *hp1 = (u16)(pk >> 16);                                        \
      hp0 += 262144; hp1 += 262144; }

#define ANFILL(AN, XA_)                                                              \
    _Pragma("unroll") for (int g = 0; g < 4; ++g) {                                  \
      f32x4 z; z[0]=gbr[g]; z[1]=gbr[g]; z[2]=gbr[g]; z[3]=gbr[g]; AN[g] = z; }      \
    __builtin_amdgcn_s_setprio(1);                                                   \
    _Pragma("unroll") for (int g = 0; g < 4; ++g)                                    \
      _Pragma("unroll") for (int c = 0; c < 4; ++c)                                  \
        AN[g] = MFMA16(XA_[c], wih[g][c], AN[g]);                                    \
    __builtin_amdgcn_s_setprio(0);

// even step: + obs pair load (top), X2 pair (T+2,T+3), X1 pair (T+4,T+5)
#define LSTEP_E(T_, RB, WB, AC, AN, X1RD, X1WR, XSLOT, SBASE) {                      \
    float2 o_[8];                                                                    \
    { int t4 = (T_) + 4 + (col >> 3); if (t4 > 127) t4 = 127; OBSROW(t4, o_); }      \
    LCORE(T_, RB, WB, AC, AN, XSLOT, xa_)                                            \
    X2P(X1RD, SBASE);                                                                \
    X1CP(o_, X1WR);                                                                  \
    ANFILL(AN, xa_)                                                                  \
    bar_lgkm();                                                                      \
  }

#define LSTEP_O(T_, RB, WB, AC, AN, XSLOT) {                                         \
    LCORE(T_, RB, WB, AC, AN, XSLOT, xa_)                                            \
    ANFILL(AN, xa_)                                                                  \
    bar_lgkm();                                                                      \
  }

  for (int tb = 0; tb < 128; tb += 4) {
    LSTEP_E(tb,     hbuf[0], hbuf[1], accA, accB, x1p[1], x1p[0], 1, 2)
    LSTEP_O(tb + 1, hbuf[1], hbuf[0], accB, accA, 2)
    LSTEP_E(tb + 2, hbuf[0], hbuf[1], accA, accB, x1p[0], x1p[1], 3, 0)
    LSTEP_O(tb + 3, hbuf[1], hbuf[0], accB, accA, 0)
  }
#undef LSTEP_E
#undef LSTEP_O
#undef LCORE
#undef ANFILL

  // final hT / cT (f32), 2 rows per lane
  {
    int k = 16 * w + col;
    out[1835008 + (n0 + rbase) * 128 + k]     = hv0;
    out[1835008 + (n0 + rbase + 1) * 128 + k] = hv1;
    out[2097152 + (n0 + rbase) * 128 + k]     = cc0;
    out[2097152 + (n0 + rbase + 1) * 128 + k] = cc1;
  }

  // drain all H stores from every wave, then compute heads from own (L2-hot) H slice
  __syncthreads();
  {
    b16x8 wh[4];
    #pragma unroll
    for (int c = 0; c < 4; ++c) wh[c] = *(const b16x8*)(Whb + col * 128 + 8 * q + 32 * c);
    const float hb = (col < 6) ? bp[col] : ((col == 6) ? bv[0] : 0.f);
    #pragma unroll
    for (int i = 0; i < 8; ++i) {
      int t0 = 16 * w + 2 * i;
      const u16* hsrc = H + ((long)(t0 + (col >> 3)) * 2048 + n0 + (col & 7)) * 128 + 8 * q;
      b16x8 a[4];
      #pragma unroll
      for (int c = 0; c < 4; ++c) a[c] = *(const b16x8*)(hsrc + 32 * c);
      f32x4 hacc = fzero4();
      #pragma unroll
      for (int c = 0; c < 4; ++c) hacc = MFMA16(a[c], wh[c], hacc);
      #pragma unroll
      for (int r = 0; r < 4; ++r) {
        int m = 4 * q + r;
        int tt = t0 + (m >> 3);
        int n = n0 + (m & 7);
        float v = hacc[r] + hb;
        if (col < 6)       out[(tt * 2048 + n) * 6 + col] = v;
        else if (col == 6) out[1572864 + tt * 2048 + n] = v;
      }
    }
  }
}

extern "C" void kernel_launch(void* const* d_in, const int* in_sizes, int n_in,
                              void* d_out, int out_size, void* d_ws, size_t ws_size,
                              hipStream_t stream) {
  const float* obs  = (const float*)d_in[0];
  const float* h0   = (const float*)d_in[1];
  const float* c0   = (const float*)d_in[2];
  const int*   done = (const int*)d_in[3];
  const float* W1   = (const float*)d_in[4];
  const float* b1   = (const float*)d_in[5];
  const float* W2   = (const float*)d_in[6];
  const float* b2   = (const float*)d_in[7];
  const float* Wih  = (const float*)d_in[8];
  const float* Whh  = (const float*)d_in[9];
  const float* bih  = (const float*)d_in[10];
  const float* bhh  = (const float*)d_in[11];
  const float* Wp   = (const float*)d_in[12];
  const float* bp   = (const float*)d_in[13];
  const float* Wv   = (const float*)d_in[14];
  const float* bv   = (const float*)d_in[15];

  char* ws = (char*)d_ws;
  u16*   H    = (u16*)(ws);                                      // 67108864 B
  u16*   W1b  = (u16*)(ws + 67108864);                           // 16384 B
  u16*   W2b  = (u16*)(ws + 67108864 + 16384);                   // 32768 B
  u16*   Wihb = (u16*)(ws + 67108864 + 16384 + 32768);           // 131072 B
  u16*   Whhb = (u16*)(ws + 67108864 + 16384 + 32768 + 131072);  // 131072 B
  u16*   Whb  = (u16*)(ws + 67108864 + 16384 + 32768 + 262144);  // 4096 B
  float* gbp  = (float*)(ws + 67108864 + 16384 + 32768 + 262144 + 4096);
  float* out  = (float*)d_out;

  hipLaunchKernelGGL(prep_kernel, dim3(256), dim3(256), 0, stream,
                     W1, W2, Wih, Whh, Wp, Wv, bih, bhh, W1b, W2b, Wihb, Whhb, Whb, gbp);
  hipLaunchKernelGGL(lstm_fused_kernel, dim3(256), dim3(512), 0, stream,
                     obs, h0, c0, done, W1b, W2b, Wihb, Whhb, Whb, gbp, b1, b2, bp, bv, H, out);
}

// Round 14
// 202.397 us; speedup vs baseline: 2.0910x; 1.1790x over previous
//
#include <hip/hip_runtime.h>

typedef __attribute__((ext_vector_type(8))) __bf16 b16x8;
typedef __attribute__((ext_vector_type(4))) float f32x4;
typedef unsigned short u16;
typedef unsigned int u32;

#define MFMA16(a, b, c) __builtin_amdgcn_mfma_f32_16x16x32_bf16((a), (b), (c), 0, 0, 0)
// XOR swizzle: spread 16B slots across banks for row-major bf16 tiles w/ 256B row stride
#define SW(byteoff, row) ((byteoff) ^ (((row) & 7) << 4))
#define LOG2E 1.4426950408889634f

__device__ __forceinline__ u16 f2bf_bits(float f) {
  union { float f; unsigned u; } v; v.f = f;
  unsigned r = (v.u + 0x7FFFu + ((v.u >> 16) & 1u)) >> 16;
  return (u16)r;
}
__device__ __forceinline__ float rcp_f(float x) { float r; asm("v_rcp_f32 %0, %1" : "=v"(r) : "v"(x)); return r; }
__device__ __forceinline__ float exp2_f(float x) { float r; asm("v_exp_f32 %0, %1" : "=v"(r) : "v"(x)); return r; }
__device__ __forceinline__ f32x4 fzero4() { f32x4 z; z[0]=0.f; z[1]=0.f; z[2]=0.f; z[3]=0.f; return z; }
__device__ __forceinline__ b16x8 bzero8() {
  b16x8 z;
  #pragma unroll
  for (int j = 0; j < 8; ++j) z[j] = (__bf16)0.f;
  return z;
}
// barrier that drains only LDS (no vmcnt drain): loads/stores fly across
__device__ __forceinline__ void bar_lgkm() {
  asm volatile("s_waitcnt lgkmcnt(0)\n\ts_barrier" ::: "memory");
}
// LSTM cell elementwise; gate pre-activations (incl. bias) already scaled by log2e
__device__ __forceinline__ void cellf(float gi, float gf, float gg, float go,
                                      float& cc, float& hv) {
  float si = rcp_f(1.f + exp2_f(-gi));
  float sf = rcp_f(1.f + exp2_f(-gf));
  float tg = 1.f - 2.f * rcp_f(1.f + exp2_f(gg + gg));
  float cn = sf * cc + si * tg;
  float so = rcp_f(1.f + exp2_f(-go));
  float tc = 1.f - 2.f * rcp_f(1.f + exp2_f(2.8853900817779268f * cn));
  cc = cn; hv = so * tc;
}

// ---------------- prep: weights -> bf16 (gate weights pre-scaled by log2e) ----------------
__global__ __launch_bounds__(256) void prep_kernel(
    const float* __restrict__ W1, const float* __restrict__ W2,
    const float* __restrict__ Wih, const float* __restrict__ Whh,
    const float* __restrict__ Wp, const float* __restrict__ Wv,
    const float* __restrict__ bih, const float* __restrict__ bhh,
    u16* __restrict__ W1b, u16* __restrict__ W2b, u16* __restrict__ Wihb,
    u16* __restrict__ Whhb, u16* __restrict__ Whb, float* __restrict__ gbp)
{
  int i = blockIdx.x * 256 + threadIdx.x;   // grid 256*256 = 65536
  if (i < 8192) {                            // W1 padded (128 x 64), K 54->64
    int r = i >> 6, k = i & 63;
    W1b[i] = f2bf_bits(k < 54 ? W1[r * 54 + k] : 0.f);
  }
  if (i < 16384) W2b[i] = f2bf_bits(W2[i]);  // 128x128
  Wihb[i] = f2bf_bits(LOG2E * Wih[i]);       // 512x128, pre-scaled
  Whhb[i] = f2bf_bits(LOG2E * Whh[i]);       // 512x128, pre-scaled
  if (i < 2048) {                            // head: rows 0-5 Wp, 6 Wv, 7-15 zero (16x128)
    int r = i >> 7, k = i & 127;
    float v = (r < 6) ? Wp[r * 128 + k] : ((r == 6) ? Wv[k] : 0.f);
    Whb[i] = f2bf_bits(v);                   // NOT scaled
  }
  if (i < 512) gbp[i] = LOG2E * (bih[i] + bhh[i]);
}

// ---------------- fused MLP + LSTM recurrence + heads ----------------
// 256 blocks x 8 batch rows, 512 threads (8 waves); wave w owns gate cols [16w,16w+16)
// AND MLP N-tile nt=w. MLP runs PAIRED (2 timesteps per M=16 tile: A-row=col, rows
// 0-7 = t, 8-15 = t+1) on EVEN steps only. obs pair loads issued at step top,
// consumed at bottom (r12 pattern — proven spill-free). xa loaded inside the ANFILL
// section (NOT hoisted: r13's xa-hoist + o_ both live = spill, FETCH 69->118MB).
// h_t -> LDS ring + global H (never read in-loop -> no vmcnt drain); heads after.
__global__ __launch_bounds__(512) void lstm_fused_kernel(
    const float* __restrict__ obs, const float* __restrict__ h0, const float* __restrict__ c0,
    const int* __restrict__ done,
    const u16* __restrict__ W1b, const u16* __restrict__ W2b,
    const u16* __restrict__ Wihb, const u16* __restrict__ Whhb, const u16* __restrict__ Whb,
    const float* __restrict__ gb, const float* __restrict__ b1v, const float* __restrict__ b2v,
    const float* __restrict__ bp, const float* __restrict__ bv,
    u16* __restrict__ H, float* __restrict__ out)
{
  __shared__ u16 hbuf[2][8 * 128];   // ping-pong h tiles (swizzled)
  __shared__ u16 x1p[2][16 * 128];   // X1 PAIR ring (2 timesteps per buffer, swizzled)
  __shared__ u16 xtl[4][8 * 128];    // gate-input x ring, slot = t & 3 (swizzled)
  __shared__ int dsh[1024];          // done[t][0..7] staged
  const int tid = threadIdx.x;
  const int w   = tid >> 6;
  const int l   = tid & 63;
  const int col = l & 15;
  const int q   = l >> 4;
  const int cl  = col & 7;
  const int n0  = blockIdx.x * 8;    // 256 blocks * 8 rows = 2048
  const int rbase = ((q & 1) << 2) + ((q >> 1) << 1);

  // resident gate-weight fragments (pre-scaled by log2e)
  b16x8 wih[4][4], whh[4][4];
  #pragma unroll
  for (int g = 0; g < 4; ++g) {
    int nt = 8 * g + w;
    #pragma unroll
    for (int c = 0; c < 4; ++c) {
      wih[g][c] = *(const b16x8*)(Wihb + (nt * 16 + col) * 128 + 8 * q + 32 * c);
      whh[g][c] = *(const b16x8*)(Whhb + (nt * 16 + col) * 128 + 8 * q + 32 * c);
    }
  }
  float gbr[4];
  #pragma unroll
  for (int g = 0; g < 4; ++g) gbr[g] = gb[(8 * g + w) * 16 + col];

  // resident MLP weight fragments for N-tile nt=w
  b16x8 w1f[2], w2f[4];
  #pragma unroll
  for (int c = 0; c < 2; ++c) w1f[c] = *(const b16x8*)(W1b + (w * 16 + col) * 64 + 8 * q + 32 * c);
  #pragma unroll
  for (int c = 0; c < 4; ++c) w2f[c] = *(const b16x8*)(W2b + (w * 16 + col) * 128 + 8 * q + 32 * c);
  const float b1r = b1v[w * 16 + col];
  const float b2r = b2v[w * 16 + col];

  // c-state
  float cc0 = c0[(n0 + rbase) * 128 + 16 * w + col];
  float cc1 = c0[(n0 + rbase + 1) * 128 + 16 * w + col];

  // stage h0 -> hbuf[0]; done -> dsh
  #pragma unroll
  for (int j = 0; j < 2; ++j) {
    int idx = tid * 2 + j;
    int row = idx >> 7, k = idx & 127;
    *(u16*)((char*)hbuf[0] + SW(row * 256 + k * 2, row)) = f2bf_bits(h0[(n0 + row) * 128 + k]);
    dsh[idx] = done[(idx >> 3) * 2048 + n0 + (idx & 7)];
  }

  // loop-invariant LDS offsets
  int offr[4];                       // 8-row tiles (h, x): row = cl
  #pragma unroll
  for (int c = 0; c < 4; ++c) offr[c] = SW(cl * 256 + 16 * q + 64 * c, cl);
  int offp[4];                       // 16-row pair tiles (x1p): row = col
  #pragma unroll
  for (int c = 0; c < 4; ++c) offp[c] = SW(col * 256 + 16 * q + 64 * c, col);
  const int wcol2 = (16 * w + col) * 2;
  const int offw0 = SW(rbase * 256 + wcol2, rbase);
  const int offw1 = SW((rbase + 1) * 256 + wcol2, rbase + 1);
  int swoff[4];                      // X1-pair writes: rows m=4q+r (0..15), all lanes
  #pragma unroll
  for (int r = 0; r < 4; ++r) { int m = 4 * q + r; swoff[r] = SW(m * 256 + wcol2, m); }
  int swx[4];                        // X2-pair writes: row (m&7) in x-tile
  #pragma unroll
  for (int r = 0; r < 4; ++r) { int mm = (4 * q + r) & 7; swx[r] = SW(mm * 256 + wcol2, mm); }

  // obs addressing: lane reads batch row n0+cl, k = 32c+8q+2p (pairs; zeroed >=54)
  const long obl = (long)(n0 + cl) * 54;
  int koff[8]; bool kval[8];
  #pragma unroll
  for (int c = 0; c < 2; ++c)
    #pragma unroll
    for (int p = 0; p < 4; ++p) {
      int i = c * 4 + p, kk = 32 * c + 8 * q + 2 * p;
      kval[i] = (kk < 54); koff[i] = kval[i] ? kk : 0;
    }

  // H store pointers
  u16* hp0 = H + (long)(n0 + rbase) * 128 + 16 * w + col;
  u16* hp1 = H + (long)(n0 + rbase + 1) * 128 + 16 * w + col;

  // ---- MLP helpers (pair form) ----
  auto OBSROW = [&](int trow, float2 (&o)[8]) {   // per-lane timestep row
    const float* obsT = obs + (long)trow * 110592 + obl;
    #pragma unroll
    for (int i = 0; i < 8; ++i) o[i] = *(const float2*)(obsT + koff[i]);
  };
  auto X1CP = [&](const float2 (&o)[8], u16* dst) {  // pair X1: all lanes write
    b16x8 a0[2];
    #pragma unroll
    for (int c = 0; c < 2; ++c)
      #pragma unroll
      for (int p = 0; p < 4; ++p) {
        int i = c * 4 + p;
        a0[c][2 * p]     = (__bf16)(kval[i] ? o[i].x : 0.f);
        a0[c][2 * p + 1] = (__bf16)(kval[i] ? o[i].y : 0.f);
      }
    f32x4 a = fzero4();
    a = MFMA16(a0[0], w1f[0], a);
    a = MFMA16(a0[1], w1f[1], a);
    #pragma unroll
    for (int r = 0; r < 4; ++r)
      *(u16*)((char*)dst + swoff[r]) = f2bf_bits(fmaxf(a[r] + b1r, 0.f));
  };
  auto X2P = [&](const u16* src, int sbase) {     // pair X2: rows 0-7 -> slot sbase, 8-15 -> sbase+1
    b16x8 a1[4];
    #pragma unroll
    for (int c = 0; c < 4; ++c) a1[c] = *(const b16x8*)((const char*)src + offp[c]);
    f32x4 a = fzero4();
    #pragma unroll
    for (int c = 0; c < 4; ++c) a = MFMA16(a1[c], w2f[c], a);
    u16* dst = xtl[sbase + (q >> 1)];
    #pragma unroll
    for (int r = 0; r < 4; ++r)
      *(u16*)((char*)dst + swx[r]) = f2bf_bits(fmaxf(a[r] + b2r, 0.f));
  };

  // ---- prologue ----
  __syncthreads();                         // h0/dsh staged
  { float2 o[8]; OBSROW(0 + (col >> 3), o); X1CP(o, x1p[0]); }   // X1 pair (0,1)
  { float2 o[8]; OBSROW(2 + (col >> 3), o); X1CP(o, x1p[1]); }   // X1 pair (2,3)
  __syncthreads();
  X2P(x1p[0], 0);                          // x(0)->slot0, x(1)->slot1
  __syncthreads();
  f32x4 accA[4], accB[4];
  {
    b16x8 xa[4];
    #pragma unroll
    for (int c = 0; c < 4; ++c) xa[c] = *(const b16x8*)((const char*)xtl[0] + offr[c]);
    #pragma unroll
    for (int g = 0; g < 4; ++g) { f32x4 z; z[0]=gbr[g]; z[1]=gbr[g]; z[2]=gbr[g]; z[3]=gbr[g]; accA[g] = z; }
    #pragma unroll
    for (int g = 0; g < 4; ++g)
      #pragma unroll
      for (int c = 0; c < 4; ++c)
        accA[g] = MFMA16(xa[c], wih[g][c], accA[g]);
  }

  int dA = 0, dC0 = 0, dC1 = 0;
  float hv0 = 0.f, hv1 = 0.f;

// step core: h-MFMA -> cell -> h write (xa NOT hoisted — r13 spill lesson).
#define LCORE(T_, RB, WB, AC)                                                        \
    b16x8 ha[4];                                                                     \
    _Pragma("unroll") for (int c = 0; c < 4; ++c) {                                  \
      ha[c] = *(const b16x8*)((const char*)(RB) + offr[c]);                          \
      if (dA) ha[c] = bzero8();                                                      \
    }                                                                                \
    if (dC0) cc0 = 0.f;                                                              \
    if (dC1) cc1 = 0.f;                                                              \
    __builtin_amdgcn_s_setprio(1);                                                   \
    _Pragma("unroll") for (int g = 0; g < 4; ++g)                                    \
      _Pragma("unroll") for (int c = 0; c < 4; ++c)                                  \
        AC[g] = MFMA16(ha[c], whh[g][c], AC[g]);                                     \
    __builtin_amdgcn_s_setprio(0);                                                   \
    dA  = dsh[(T_) * 8 + cl];                                                        \
    dC0 = dsh[(T_) * 8 + rbase];                                                     \
    dC1 = dsh[(T_) * 8 + rbase + 1];                                                 \
    _Pragma("unroll") for (int g = 0; g < 4; ++g) {                                  \
      asm volatile("v_permlane32_swap_b32 %0, %1" : "+v"(AC[g][0]), "+v"(AC[g][2])); \
      asm volatile("v_permlane32_swap_b32 %0, %1" : "+v"(AC[g][1]), "+v"(AC[g][3])); \
    }                                                                                \
    cellf(AC[0][0], AC[1][0], AC[2][0], AC[3][0], cc0, hv0);                         \
    cellf(AC[0][1], AC[1][1], AC[2][1], AC[3][1], cc1, hv1);                         \
    { u32 pk;                                                                        \
      asm("v_cvt_pk_bf16_f32 %0, %1, %2" : "=v"(pk) : "v"(hv0), "v"(hv1));           \
      *(u16*)((char*)(WB) + offw0) = (u16)pk;                                        \
      *(u16*)((char*)(WB) + offw1) = (u16)(pk >> 16);                                \
      *hp0 = (u16)pk; *hp1 = (u16)(pk >> 16);                                        \
      hp0 += 262144; hp1 += 262144; }

#define ANFILL(AN, XSLOT)                                                            \
    { b16x8 xa[4];                                                                   \
      _Pragma("unroll") for (int c = 0; c < 4; ++c)                                  \
        xa[c] = *(const b16x8*)((const char*)xtl[XSLOT] + offr[c]);                  \
      _Pragma("unroll") for (int g = 0; g < 4; ++g) {                                \
        f32x4 z; z[0]=gbr[g]; z[1]=gbr[g]; z[2]=gbr[g]; z[3]=gbr[g]; AN[g] = z; }    \
      __builtin_amdgcn_s_setprio(1);                                                 \
      _Pragma("unroll") for (int g = 0; g < 4; ++g)                                  \
        _Pragma("unroll") for (int c = 0; c < 4; ++c)                                \
          AN[g] = MFMA16(xa[c], wih[g][c], AN[g]);                                   \
      __builtin_amdgcn_s_setprio(0);                                                 \
    }

// even step: obs pair load (top), X2 pair (T+2,T+3), X1 pair (T+4,T+5)
#define LSTEP_E(T_, RB, WB, AC, AN, X1RD, X1WR, XSLOT, SBASE) {                      \
    float2 o_[8];                                                                    \
    { int t4 = (T_) + 4 + (col >> 3); if (t4 > 127) t4 = 127; OBSROW(t4, o_); }      \
    LCORE(T_, RB, WB, AC)                                                            \
    X2P(X1RD, SBASE);                                                                \
    ANFILL(AN, XSLOT)                                                                \
    X1CP(o_, X1WR);                                                                  \
    bar_lgkm();                                                                      \
  }

#define LSTEP_O(T_, RB, WB, AC, AN, XSLOT) {                                         \
    LCORE(T_, RB, WB, AC)                                                            \
    ANFILL(AN, XSLOT)                                                                \
    bar_lgkm();                                                                      \
  }

  for (int tb = 0; tb < 128; tb += 4) {
    LSTEP_E(tb,     hbuf[0], hbuf[1], accA, accB, x1p[1], x1p[0], 1, 2)
    LSTEP_O(tb + 1, hbuf[1], hbuf[0], accB, accA, 2)
    LSTEP_E(tb + 2, hbuf[0], hbuf[1], accA, accB, x1p[0], x1p[1], 3, 0)
    LSTEP_O(tb + 3, hbuf[1], hbuf[0], accB, accA, 0)
  }
#undef LSTEP_E
#undef LSTEP_O
#undef LCORE
#undef ANFILL

  // final hT / cT (f32), 2 rows per lane
  {
    int k = 16 * w + col;
    out[1835008 + (n0 + rbase) * 128 + k]     = hv0;
    out[1835008 + (n0 + rbase + 1) * 128 + k] = hv1;
    out[2097152 + (n0 + rbase) * 128 + k]     = cc0;
    out[2097152 + (n0 + rbase + 1) * 128 + k] = cc1;
  }

  // drain all H stores from every wave, then compute heads from own (L2-hot) H slice
  __syncthreads();
  {
    b16x8 wh[4];
    #pragma unroll
    for (int c = 0; c < 4; ++c) wh[c] = *(const b16x8*)(Whb + col * 128 + 8 * q + 32 * c);
    const float hb = (col < 6) ? bp[col] : ((col == 6) ? bv[0] : 0.f);
    #pragma unroll
    for (int i = 0; i < 8; ++i) {
      int t0 = 16 * w + 2 * i;
      const u16* hsrc = H + ((long)(t0 + (col >> 3)) * 2048 + n0 + (col & 7)) * 128 + 8 * q;
      b16x8 a[4];
      #pragma unroll
      for (int c = 0; c < 4; ++c) a[c] = *(const b16x8*)(hsrc + 32 * c);
      f32x4 hacc = fzero4();
      #pragma unroll
      for (int c = 0; c < 4; ++c) hacc = MFMA16(a[c], wh[c], hacc);
      #pragma unroll
      for (int r = 0; r < 4; ++r) {
        int m = 4 * q + r;
        int tt = t0 + (m >> 3);
        int n = n0 + (m & 7);
        float v = hacc[r] + hb;
        if (col < 6)       out[(tt * 2048 + n) * 6 + col] = v;
        else if (col == 6) out[1572864 + tt * 2048 + n] = v;
      }
    }
  }
}

extern "C" void kernel_launch(void* const* d_in, const int* in_sizes, int n_in,
                              void* d_out, int out_size, void* d_ws, size_t ws_size,
                              hipStream_t stream) {
  const float* obs  = (const float*)d_in[0];
  const float* h0   = (const float*)d_in[1];
  const float* c0   = (const float*)d_in[2];
  const int*   done = (const int*)d_in[3];
  const float* W1   = (const float*)d_in[4];
  const float* b1   = (const float*)d_in[5];
  const float* W2   = (const float*)d_in[6];
  const float* b2   = (const float*)d_in[7];
  const float* Wih  = (const float*)d_in[8];
  const float* Whh  = (const float*)d_in[9];
  const float* bih  = (const float*)d_in[10];
  const float* bhh  = (const float*)d_in[11];
  const float* Wp   = (const float*)d_in[12];
  const float* bp   = (const float*)d_in[13];
  const float* Wv   = (const float*)d_in[14];
  const float* bv   = (const float*)d_in[15];

  char* ws = (char*)d_ws;
  u16*   H    = (u16*)(ws);                                      // 67108864 B
  u16*   W1b  = (u16*)(ws + 67108864);                           // 16384 B
  u16*   W2b  = (u16*)(ws + 67108864 + 16384);                   // 32768 B
  u16*   Wihb = (u16*)(ws + 67108864 + 16384 + 32768);           // 131072 B
  u16*   Whhb = (u16*)(ws + 67108864 + 16384 + 32768 + 131072);  // 131072 B
  u16*   Whb  = (u16*)(ws + 67108864 + 16384 + 32768 + 262144);  // 4096 B
  float* gbp  = (float*)(ws + 67108864 + 16384 + 32768 + 262144 + 4096);
  float* out  = (float*)d_out;

  hipLaunchKernelGGL(prep_kernel, dim3(256), dim3(256), 0, stream,
                     W1, W2, Wih, Whh, Wp, Wv, bih, bhh, W1b, W2b, Wihb, Whhb, Whb, gbp);
  hipLaunchKernelGGL(lstm_fused_kernel, dim3(256), dim3(512), 0, stream,
                     obs, h0, c0, done, W1b, W2b, Wihb, Whhb, Whb, gbp, b1, b2, bp, bv, H, out);
}

// Round 15
// 190.059 us; speedup vs baseline: 2.2267x; 1.0649x over previous
//
#include <hip/hip_runtime.h>

typedef __attribute__((ext_vector_type(8))) __bf16 b16x8;
typedef __attribute__((ext_vector_type(4))) float f32x4;
typedef unsigned short u16;
typedef unsigned int u32;

#define MFMA16(a, b, c) __builtin_amdgcn_mfma_f32_16x16x32_bf16((a), (b), (c), 0, 0, 0)
// XOR swizzle: spread 16B slots across banks for row-major bf16 tiles w/ 256B row stride
#define SW(byteoff, row) ((byteoff) ^ (((row) & 7) << 4))
#define LOG2E 1.4426950408889634f

__device__ __forceinline__ u16 f2bf_bits(float f) {
  union { float f; unsigned u; } v; v.f = f;
  unsigned r = (v.u + 0x7FFFu + ((v.u >> 16) & 1u)) >> 16;
  return (u16)r;
}
__device__ __forceinline__ float rcp_f(float x) { float r; asm("v_rcp_f32 %0, %1" : "=v"(r) : "v"(x)); return r; }
__device__ __forceinline__ float exp2_f(float x) { float r; asm("v_exp_f32 %0, %1" : "=v"(r) : "v"(x)); return r; }
__device__ __forceinline__ f32x4 fzero4() { f32x4 z; z[0]=0.f; z[1]=0.f; z[2]=0.f; z[3]=0.f; return z; }
// barrier that drains only LDS (no vmcnt drain): loads/stores fly across
__device__ __forceinline__ void bar_lgkm() {
  asm volatile("s_waitcnt lgkmcnt(0)\n\ts_barrier" ::: "memory");
}
// LSTM cell elementwise; gate pre-activations (incl. bias) already scaled by log2e
__device__ __forceinline__ void cellf(float gi, float gf, float gg, float go,
                                      float& cc, float& hv) {
  float si = rcp_f(1.f + exp2_f(-gi));
  float sf = rcp_f(1.f + exp2_f(-gf));
  float tg = 1.f - 2.f * rcp_f(1.f + exp2_f(gg + gg));
  float cn = sf * cc + si * tg;
  float so = rcp_f(1.f + exp2_f(-go));
  float tc = 1.f - 2.f * rcp_f(1.f + exp2_f(2.8853900817779268f * cn));
  cc = cn; hv = so * tc;
}

// ---------------- prep: weights -> bf16 (gate weights pre-scaled by log2e) ----------------
__global__ __launch_bounds__(256) void prep_kernel(
    const float* __restrict__ W1, const float* __restrict__ W2,
    const float* __restrict__ Wih, const float* __restrict__ Whh,
    const float* __restrict__ Wp, const float* __restrict__ Wv,
    const float* __restrict__ bih, const float* __restrict__ bhh,
    u16* __restrict__ W1b, u16* __restrict__ W2b, u16* __restrict__ Wihb,
    u16* __restrict__ Whhb, u16* __restrict__ Whb, float* __restrict__ gbp)
{
  int i = blockIdx.x * 256 + threadIdx.x;   // grid 256*256 = 65536
  if (i < 8192) {                            // W1 padded (128 x 64), K 54->64
    int r = i >> 6, k = i & 63;
    W1b[i] = f2bf_bits(k < 54 ? W1[r * 54 + k] : 0.f);
  }
  if (i < 16384) W2b[i] = f2bf_bits(W2[i]);  // 128x128
  Wihb[i] = f2bf_bits(LOG2E * Wih[i]);       // 512x128, pre-scaled
  Whhb[i] = f2bf_bits(LOG2E * Whh[i]);       // 512x128, pre-scaled
  if (i < 2048) {                            // head: rows 0-5 Wp, 6 Wv, 7-15 zero (16x128)
    int r = i >> 7, k = i & 127;
    float v = (r < 6) ? Wp[r * 128 + k] : ((r == 6) ? Wv[k] : 0.f);
    Whb[i] = f2bf_bits(v);                   // NOT scaled
  }
  if (i < 512) gbp[i] = LOG2E * (bih[i] + bhh[i]);
}

// ---------------- fused MLP + LSTM recurrence + heads ----------------
// 256 blocks x 8 batch rows, 512 threads (8 waves); wave w owns gate cols [16w,16w+16)
// AND MLP N-tile nt=w. MLP runs PAIRED (2 timesteps per M=16 tile) on EVEN steps.
// obs pair loads issued at step top, consumed at bottom (spill-free r12 pattern).
// done-mask applied on the hbuf WRITE side (dC0/dC1 = done[T] are live at write
// time): 2 cndmask/lane vs 16 for read-side fragment zeroing; read side is maskless.
// h_t -> LDS ring (masked) + global H (unmasked; never read in-loop -> no vmcnt
// drain); heads after the loop from L2-hot H.
__global__ __launch_bounds__(512) void lstm_fused_kernel(
    const float* __restrict__ obs, const float* __restrict__ h0, const float* __restrict__ c0,
    const int* __restrict__ done,
    const u16* __restrict__ W1b, const u16* __restrict__ W2b,
    const u16* __restrict__ Wihb, const u16* __restrict__ Whhb, const u16* __restrict__ Whb,
    const float* __restrict__ gb, const float* __restrict__ b1v, const float* __restrict__ b2v,
    const float* __restrict__ bp, const float* __restrict__ bv,
    u16* __restrict__ H, float* __restrict__ out)
{
  __shared__ u16 hbuf[2][8 * 128];   // ping-pong h tiles (swizzled, write-side masked)
  __shared__ u16 x1p[2][16 * 128];   // X1 PAIR ring (2 timesteps per buffer, swizzled)
  __shared__ u16 xtl[4][8 * 128];    // gate-input x ring, slot = t & 3 (swizzled)
  __shared__ int dsh[1024];          // done[t][0..7] staged
  const int tid = threadIdx.x;
  const int w   = tid >> 6;
  const int l   = tid & 63;
  const int col = l & 15;
  const int q   = l >> 4;
  const int cl  = col & 7;
  const int n0  = blockIdx.x * 8;    // 256 blocks * 8 rows = 2048
  const int rbase = ((q & 1) << 2) + ((q >> 1) << 1);

  // resident gate-weight fragments (pre-scaled by log2e)
  b16x8 wih[4][4], whh[4][4];
  #pragma unroll
  for (int g = 0; g < 4; ++g) {
    int nt = 8 * g + w;
    #pragma unroll
    for (int c = 0; c < 4; ++c) {
      wih[g][c] = *(const b16x8*)(Wihb + (nt * 16 + col) * 128 + 8 * q + 32 * c);
      whh[g][c] = *(const b16x8*)(Whhb + (nt * 16 + col) * 128 + 8 * q + 32 * c);
    }
  }
  float gbr[4];
  #pragma unroll
  for (int g = 0; g < 4; ++g) gbr[g] = gb[(8 * g + w) * 16 + col];

  // resident MLP weight fragments for N-tile nt=w
  b16x8 w1f[2], w2f[4];
  #pragma unroll
  for (int c = 0; c < 2; ++c) w1f[c] = *(const b16x8*)(W1b + (w * 16 + col) * 64 + 8 * q + 32 * c);
  #pragma unroll
  for (int c = 0; c < 4; ++c) w2f[c] = *(const b16x8*)(W2b + (w * 16 + col) * 128 + 8 * q + 32 * c);
  const float b1r = b1v[w * 16 + col];
  const float b2r = b2v[w * 16 + col];

  // c-state
  float cc0 = c0[(n0 + rbase) * 128 + 16 * w + col];
  float cc1 = c0[(n0 + rbase + 1) * 128 + 16 * w + col];

  // stage h0 -> hbuf[0] (unmasked: d_prev[0]=0); done -> dsh
  #pragma unroll
  for (int j = 0; j < 2; ++j) {
    int idx = tid * 2 + j;
    int row = idx >> 7, k = idx & 127;
    *(u16*)((char*)hbuf[0] + SW(row * 256 + k * 2, row)) = f2bf_bits(h0[(n0 + row) * 128 + k]);
    dsh[idx] = done[(idx >> 3) * 2048 + n0 + (idx & 7)];
  }

  // loop-invariant LDS offsets
  int offr[4];                       // 8-row tiles (h, x): row = cl
  #pragma unroll
  for (int c = 0; c < 4; ++c) offr[c] = SW(cl * 256 + 16 * q + 64 * c, cl);
  int offp[4];                       // 16-row pair tiles (x1p): row = col
  #pragma unroll
  for (int c = 0; c < 4; ++c) offp[c] = SW(col * 256 + 16 * q + 64 * c, col);
  const int wcol2 = (16 * w + col) * 2;
  const int offw0 = SW(rbase * 256 + wcol2, rbase);
  const int offw1 = SW((rbase + 1) * 256 + wcol2, rbase + 1);
  int swoff[4];                      // X1-pair writes: rows m=4q+r (0..15), all lanes
  #pragma unroll
  for (int r = 0; r < 4; ++r) { int m = 4 * q + r; swoff[r] = SW(m * 256 + wcol2, m); }
  int swx[4];                        // X2-pair writes: row (m&7) in x-tile
  #pragma unroll
  for (int r = 0; r < 4; ++r) { int mm = (4 * q + r) & 7; swx[r] = SW(mm * 256 + wcol2, mm); }

  // obs addressing: lane reads batch row n0+cl, k = 32c+8q+2p (pairs; zeroed >=54)
  const long obl = (long)(n0 + cl) * 54;
  int koff[8]; bool kval[8];
  #pragma unroll
  for (int c = 0; c < 2; ++c)
    #pragma unroll
    for (int p = 0; p < 4; ++p) {
      int i = c * 4 + p, kk = 32 * c + 8 * q + 2 * p;
      kval[i] = (kk < 54); koff[i] = kval[i] ? kk : 0;
    }

  // H store pointers
  u16* hp0 = H + (long)(n0 + rbase) * 128 + 16 * w + col;
  u16* hp1 = H + (long)(n0 + rbase + 1) * 128 + 16 * w + col;

  // ---- MLP helpers (pair form) ----
  auto OBSROW = [&](int trow, float2 (&o)[8]) {   // per-lane timestep row
    const float* obsT = obs + (long)trow * 110592 + obl;
    #pragma unroll
    for (int i = 0; i < 8; ++i) o[i] = *(const float2*)(obsT + koff[i]);
  };
  auto X1CP = [&](const float2 (&o)[8], u16* dst) {  // pair X1: all lanes write
    b16x8 a0[2];
    #pragma unroll
    for (int c = 0; c < 2; ++c)
      #pragma unroll
      for (int p = 0; p < 4; ++p) {
        int i = c * 4 + p;
        a0[c][2 * p]     = (__bf16)(kval[i] ? o[i].x : 0.f);
        a0[c][2 * p + 1] = (__bf16)(kval[i] ? o[i].y : 0.f);
      }
    f32x4 a = fzero4();
    a = MFMA16(a0[0], w1f[0], a);
    a = MFMA16(a0[1], w1f[1], a);
    #pragma unroll
    for (int r = 0; r < 4; ++r)
      *(u16*)((char*)dst + swoff[r]) = f2bf_bits(fmaxf(a[r] + b1r, 0.f));
  };
  auto X2P = [&](const u16* src, int sbase) {     // pair X2: rows 0-7 -> slot sbase, 8-15 -> sbase+1
    b16x8 a1[4];
    #pragma unroll
    for (int c = 0; c < 4; ++c) a1[c] = *(const b16x8*)((const char*)src + offp[c]);
    f32x4 a = fzero4();
    #pragma unroll
    for (int c = 0; c < 4; ++c) a = MFMA16(a1[c], w2f[c], a);
    u16* dst = xtl[sbase + (q >> 1)];
    #pragma unroll
    for (int r = 0; r < 4; ++r)
      *(u16*)((char*)dst + swx[r]) = f2bf_bits(fmaxf(a[r] + b2r, 0.f));
  };

  // ---- prologue ----
  __syncthreads();                         // h0/dsh staged
  { float2 o[8]; OBSROW(0 + (col >> 3), o); X1CP(o, x1p[0]); }   // X1 pair (0,1)
  { float2 o[8]; OBSROW(2 + (col >> 3), o); X1CP(o, x1p[1]); }   // X1 pair (2,3)
  __syncthreads();
  X2P(x1p[0], 0);                          // x(0)->slot0, x(1)->slot1
  __syncthreads();
  f32x4 accA[4], accB[4];
  {
    b16x8 xa[4];
    #pragma unroll
    for (int c = 0; c < 4; ++c) xa[c] = *(const b16x8*)((const char*)xtl[0] + offr[c]);
    #pragma unroll
    for (int g = 0; g < 4; ++g) { f32x4 z; z[0]=gbr[g]; z[1]=gbr[g]; z[2]=gbr[g]; z[3]=gbr[g]; accA[g] = z; }
    #pragma unroll
    for (int g = 0; g < 4; ++g)
      #pragma unroll
      for (int c = 0; c < 4; ++c)
        accA[g] = MFMA16(xa[c], wih[g][c], accA[g]);
  }

  int dC0 = 0, dC1 = 0;
  float hv0 = 0.f, hv1 = 0.f;

// step core: maskless h-MFMA (hbuf pre-masked on write) -> cell -> masked h write.
// dC0/dC1 at cell time = done[T-1] (masks c); after reload = done[T] (masks write).
#define LCORE(T_, RB, WB, AC)                                                        \
    b16x8 ha[4];                                                                     \
    _Pragma("unroll") for (int c = 0; c < 4; ++c)                                    \
      ha[c] = *(const b16x8*)((const char*)(RB) + offr[c]);                          \
    if (dC0) cc0 = 0.f;                                                              \
    if (dC1) cc1 = 0.f;                                                              \
    __builtin_amdgcn_s_setprio(1);                                                   \
    _Pragma("unroll") for (int g = 0; g < 4; ++g)                                    \
      _Pragma("unroll") for (int c = 0; c < 4; ++c)                                  \
        AC[g] = MFMA16(ha[c], whh[g][c], AC[g]);                                     \
    __builtin_amdgcn_s_setprio(0);                                                   \
    dC0 = dsh[(T_) * 8 + rbase];                                                     \
    dC1 = dsh[(T_) * 8 + rbase + 1];                                                 \
    _Pragma("unroll") for (int g = 0; g < 4; ++g) {                                  \
      asm volatile("v_permlane32_swap_b32 %0, %1" : "+v"(AC[g][0]), "+v"(AC[g][2])); \
      asm volatile("v_permlane32_swap_b32 %0, %1" : "+v"(AC[g][1]), "+v"(AC[g][3])); \
    }                                                                                \
    cellf(AC[0][0], AC[1][0], AC[2][0], AC[3][0], cc0, hv0);                         \
    cellf(AC[0][1], AC[1][1], AC[2][1], AC[3][1], cc1, hv1);                         \
    { u32 pk;                                                                        \
      asm("v_cvt_pk_bf16_f32 %0, %1, %2" : "=v"(pk) : "v"(hv0), "v"(hv1));           \
      *(u16*)((char*)(WB) + offw0) = dC0 ? (u16)0 : (u16)pk;                         \
      *(u16*)((char*)(WB) + offw1) = dC1 ? (u16)0 : (u16)(pk >> 16);                 \
      *hp0 = (u16)pk; *hp1 = (u16)(pk >> 16);                                        \
      hp0 += 262144; hp1 += 262144; }

#define ANFILL(AN, XSLOT)                                                            \
    { b16x8 xa[4];                                                                   \
      _Pragma("unroll") for (int c = 0; c < 4; ++c)                                  \
        xa[c] = *(const b16x8*)((const char*)xtl[XSLOT] + offr[c]);                  \
      _Pragma("unroll") for (int g = 0; g < 4; ++g) {                                \
        f32x4 z; z[0]=gbr[g]; z[1]=gbr[g]; z[2]=gbr[g]; z[3]=gbr[g]; AN[g] = z; }    \
      __builtin_amdgcn_s_setprio(1);                                                 \
      _Pragma("unroll") for (int g = 0; g < 4; ++g)                                  \
        _Pragma("unroll") for (int c = 0; c < 4; ++c)                                \
          AN[g] = MFMA16(xa[c], wih[g][c], AN[g]);                                   \
      __builtin_amdgcn_s_setprio(0);                                                 \
    }

// even step: obs pair load (top), X2 pair (T+2,T+3), X1 pair (T+4,T+5)
#define LSTEP_E(T_, RB, WB, AC, AN, X1RD, X1WR, XSLOT, SBASE) {                      \
    float2 o_[8];                                                                    \
    { int t4 = (T_) + 4 + (col >> 3); if (t4 > 127) t4 = 127; OBSROW(t4, o_); }      \
    LCORE(T_, RB, WB, AC)                                                            \
    X2P(X1RD, SBASE);                                                                \
    ANFILL(AN, XSLOT)                                                                \
    X1CP(o_, X1WR);                                                                  \
    bar_lgkm();                                                                      \
  }

#define LSTEP_O(T_, RB, WB, AC, AN, XSLOT) {                                         \
    LCORE(T_, RB, WB, AC)                                                            \
    ANFILL(AN, XSLOT)                                                                \
    bar_lgkm();                                                                      \
  }

  for (int tb = 0; tb < 128; tb += 4) {
    LSTEP_E(tb,     hbuf[0], hbuf[1], accA, accB, x1p[1], x1p[0], 1, 2)
    LSTEP_O(tb + 1, hbuf[1], hbuf[0], accB, accA, 2)
    LSTEP_E(tb + 2, hbuf[0], hbuf[1], accA, accB, x1p[0], x1p[1], 3, 0)
    LSTEP_O(tb + 3, hbuf[1], hbuf[0], accB, accA, 0)
  }
#undef LSTEP_E
#undef LSTEP_O
#undef LCORE
#undef ANFILL

  // final hT / cT (f32), 2 rows per lane
  {
    int k = 16 * w + col;
    out[1835008 + (n0 + rbase) * 128 + k]     = hv0;
    out[1835008 + (n0 + rbase + 1) * 128 + k] = hv1;
    out[2097152 + (n0 + rbase) * 128 + k]     = cc0;
    out[2097152 + (n0 + rbase + 1) * 128 + k] = cc1;
  }

  // drain all H stores from every wave, then compute heads from own (L2-hot) H slice
  __syncthreads();
  {
    b16x8 wh[4];
    #pragma unroll
    for (int c = 0; c < 4; ++c) wh[c] = *(const b16x8*)(Whb + col * 128 + 8 * q + 32 * c);
    const float hb = (col < 6) ? bp[col] : ((col == 6) ? bv[0] : 0.f);
    #pragma unroll
    for (int i = 0; i < 8; ++i) {
      int t0 = 16 * w + 2 * i;
      const u16* hsrc = H + ((long)(t0 + (col >> 3)) * 2048 + n0 + (col & 7)) * 128 + 8 * q;
      b16x8 a[4];
      #pragma unroll
      for (int c = 0; c < 4; ++c) a[c] = *(const b16x8*)(hsrc + 32 * c);
      f32x4 hacc = fzero4();
      #pragma unroll
      for (int c = 0; c < 4; ++c) hacc = MFMA16(a[c], wh[c], hacc);
      #pragma unroll
      for (int r = 0; r < 4; ++r) {
        int m = 4 * q + r;
        int tt = t0 + (m >> 3);
        int n = n0 + (m & 7);
        float v = hacc[r] + hb;
        if (col < 6)       out[(tt * 2048 + n) * 6 + col] = v;
        else if (col == 6) out[1572864 + tt * 2048 + n] = v;
      }
    }
  }
}

extern "C" void kernel_launch(void* const* d_in, const int* in_sizes, int n_in,
                              void* d_out, int out_size, void* d_ws, size_t ws_size,
                              hipStream_t stream) {
  const float* obs  = (const float*)d_in[0];
  const float* h0   = (const float*)d_in[1];
  const float* c0   = (const float*)d_in[2];
  const int*   done = (const int*)d_in[3];
  const float* W1   = (const float*)d_in[4];
  const float* b1   = (const float*)d_in[5];
  const float* W2   = (const float*)d_in[6];
  const float* b2   = (const float*)d_in[7];
  const float* Wih  = (const float*)d_in[8];
  const float* Whh  = (const float*)d_in[9];
  const float* bih  = (const float*)d_in[10];
  const float* bhh  = (const float*)d_in[11];
  const float* Wp   = (const float*)d_in[12];
  const float* bp   = (const float*)d_in[13];
  const float* Wv   = (const float*)d_in[14];
  const float* bv   = (const float*)d_in[15];

  char* ws = (char*)d_ws;
  u16*   H    = (u16*)(ws);                                      // 67108864 B
  u16*   W1b  = (u16*)(ws + 67108864);                           // 16384 B
  u16*   W2b  = (u16*)(ws + 67108864 + 16384);                   // 32768 B
  u16*   Wihb = (u16*)(ws + 67108864 + 16384 + 32768);           // 131072 B
  u16*   Whhb = (u16*)(ws + 67108864 + 16384 + 32768 + 131072);  // 131072 B
  u16*   Whb  = (u16*)(ws + 67108864 + 16384 + 32768 + 262144);  // 4096 B
  float* gbp  = (float*)(ws + 67108864 + 16384 + 32768 + 262144 + 4096);
  float* out  = (float*)d_out;

  hipLaunchKernelGGL(prep_kernel, dim3(256), dim3(256), 0, stream,
                     W1, W2, Wih, Whh, Wp, Wv, bih, bhh, W1b, W2b, Wihb, Whhb, Whb, gbp);
  hipLaunchKernelGGL(lstm_fused_kernel, dim3(256), dim3(512), 0, stream,
                     obs, h0, c0, done, W1b, W2b, Wihb, Whhb, Whb, gbp, b1, b2, bp, bv, H, out);
}

// Round 16
// 189.679 us; speedup vs baseline: 2.2312x; 1.0020x over previous
//
#include <hip/hip_runtime.h>

typedef __attribute__((ext_vector_type(8))) __bf16 b16x8;
typedef __attribute__((ext_vector_type(4))) float f32x4;
typedef unsigned short u16;
typedef unsigned int u32;

#define MFMA16(a, b, c) __builtin_amdgcn_mfma_f32_16x16x32_bf16((a), (b), (c), 0, 0, 0)
// XOR swizzle: spread 16B slots across banks for row-major bf16 tiles w/ 256B row stride
#define SW(byteoff, row) ((byteoff) ^ (((row) & 7) << 4))
#define LOG2E 1.4426950408889634f

__device__ __forceinline__ u16 f2bf_bits(float f) {
  union { float f; unsigned u; } v; v.f = f;
  unsigned r = (v.u + 0x7FFFu + ((v.u >> 16) & 1u)) >> 16;
  return (u16)r;
}
__device__ __forceinline__ float rcp_f(float x) { float r; asm("v_rcp_f32 %0, %1" : "=v"(r) : "v"(x)); return r; }
__device__ __forceinline__ float exp2_f(float x) { float r; asm("v_exp_f32 %0, %1" : "=v"(r) : "v"(x)); return r; }
__device__ __forceinline__ f32x4 fzero4() { f32x4 z; z[0]=0.f; z[1]=0.f; z[2]=0.f; z[3]=0.f; return z; }
// barrier that drains only LDS (no vmcnt drain): loads/stores fly across
__device__ __forceinline__ void bar_lgkm() {
  asm volatile("s_waitcnt lgkmcnt(0)\n\ts_barrier" ::: "memory");
}
// LSTM cell elementwise; gate pre-activations (incl. bias) already scaled by log2e
__device__ __forceinline__ void cellf(float gi, float gf, float gg, float go,
                                      float& cc, float& hv) {
  float si = rcp_f(1.f + exp2_f(-gi));
  float sf = rcp_f(1.f + exp2_f(-gf));
  float tg = 1.f - 2.f * rcp_f(1.f + exp2_f(gg + gg));
  float cn = sf * cc + si * tg;
  float so = rcp_f(1.f + exp2_f(-go));
  float tc = 1.f - 2.f * rcp_f(1.f + exp2_f(2.8853900817779268f * cn));
  cc = cn; hv = so * tc;
}

// ---------------- prep: weights -> bf16 (gate weights pre-scaled by log2e) ----------------
__global__ __launch_bounds__(256) void prep_kernel(
    const float* __restrict__ W1, const float* __restrict__ W2,
    const float* __restrict__ Wih, const float* __restrict__ Whh,
    const float* __restrict__ Wp, const float* __restrict__ Wv,
    const float* __restrict__ bih, const float* __restrict__ bhh,
    u16* __restrict__ W1b, u16* __restrict__ W2b, u16* __restrict__ Wihb,
    u16* __restrict__ Whhb, u16* __restrict__ Whb, float* __restrict__ gbp)
{
  int i = blockIdx.x * 256 + threadIdx.x;   // grid 256*256 = 65536
  if (i < 8192) {                            // W1 padded (128 x 64), K 54->64
    int r = i >> 6, k = i & 63;
    W1b[i] = f2bf_bits(k < 54 ? W1[r * 54 + k] : 0.f);
  }
  if (i < 16384) W2b[i] = f2bf_bits(W2[i]);  // 128x128
  Wihb[i] = f2bf_bits(LOG2E * Wih[i]);       // 512x128, pre-scaled
  Whhb[i] = f2bf_bits(LOG2E * Whh[i]);       // 512x128, pre-scaled
  if (i < 2048) {                            // head: rows 0-5 Wp, 6 Wv, 7-15 zero (16x128)
    int r = i >> 7, k = i & 127;
    float v = (r < 6) ? Wp[r * 128 + k] : ((r == 6) ? Wv[k] : 0.f);
    Whb[i] = f2bf_bits(v);                   // NOT scaled
  }
  if (i < 512) gbp[i] = LOG2E * (bih[i] + bhh[i]);
}

// ---------------- fused MLP + LSTM recurrence + heads ----------------
// 256 blocks x 8 batch rows, 512 threads (8 waves); wave w owns gate cols [16w,16w+16)
// AND MLP N-tile nt=w. MLP is PAIRED (2 timesteps per M=16 tile) and BALANCED across
// step parity: EVEN steps run X2P (pair (T+2,T+3)); ODD steps run obs-load + X1CP
// (pair (T+3,T+4), consumed by X2P one barrier later). This evens out per-step work
// (r15 had all MLP on even steps -> barrier lockstep wasted odd-step headroom).
// obs loads issued at step top, consumed at bottom (spill-free r12 pattern).
// done-mask on the hbuf WRITE side (2 cndmask/lane). h_t -> LDS ring (masked) +
// global H (unmasked; never read in-loop -> no vmcnt drain); heads after the loop.
__global__ __launch_bounds__(512) void lstm_fused_kernel(
    const float* __restrict__ obs, const float* __restrict__ h0, const float* __restrict__ c0,
    const int* __restrict__ done,
    const u16* __restrict__ W1b, const u16* __restrict__ W2b,
    const u16* __restrict__ Wihb, const u16* __restrict__ Whhb, const u16* __restrict__ Whb,
    const float* __restrict__ gb, const float* __restrict__ b1v, const float* __restrict__ b2v,
    const float* __restrict__ bp, const float* __restrict__ bv,
    u16* __restrict__ H, float* __restrict__ out)
{
  __shared__ u16 hbuf[2][8 * 128];   // ping-pong h tiles (swizzled, write-side masked)
  __shared__ u16 x1p[2][16 * 128];   // X1 PAIR ring (2 timesteps per buffer, swizzled)
  __shared__ u16 xtl[4][8 * 128];    // gate-input x ring, slot = t & 3 (swizzled)
  __shared__ int dsh[1024];          // done[t][0..7] staged
  const int tid = threadIdx.x;
  const int w   = tid >> 6;
  const int l   = tid & 63;
  const int col = l & 15;
  const int q   = l >> 4;
  const int cl  = col & 7;
  const int n0  = blockIdx.x * 8;    // 256 blocks * 8 rows = 2048
  const int rbase = ((q & 1) << 2) + ((q >> 1) << 1);

  // resident gate-weight fragments (pre-scaled by log2e)
  b16x8 wih[4][4], whh[4][4];
  #pragma unroll
  for (int g = 0; g < 4; ++g) {
    int nt = 8 * g + w;
    #pragma unroll
    for (int c = 0; c < 4; ++c) {
      wih[g][c] = *(const b16x8*)(Wihb + (nt * 16 + col) * 128 + 8 * q + 32 * c);
      whh[g][c] = *(const b16x8*)(Whhb + (nt * 16 + col) * 128 + 8 * q + 32 * c);
    }
  }
  float gbr[4];
  #pragma unroll
  for (int g = 0; g < 4; ++g) gbr[g] = gb[(8 * g + w) * 16 + col];

  // resident MLP weight fragments for N-tile nt=w
  b16x8 w1f[2], w2f[4];
  #pragma unroll
  for (int c = 0; c < 2; ++c) w1f[c] = *(const b16x8*)(W1b + (w * 16 + col) * 64 + 8 * q + 32 * c);
  #pragma unroll
  for (int c = 0; c < 4; ++c) w2f[c] = *(const b16x8*)(W2b + (w * 16 + col) * 128 + 8 * q + 32 * c);
  const float b1r = b1v[w * 16 + col];
  const float b2r = b2v[w * 16 + col];

  // c-state
  float cc0 = c0[(n0 + rbase) * 128 + 16 * w + col];
  float cc1 = c0[(n0 + rbase + 1) * 128 + 16 * w + col];

  // stage h0 -> hbuf[0] (unmasked: d_prev[0]=0); done -> dsh
  #pragma unroll
  for (int j = 0; j < 2; ++j) {
    int idx = tid * 2 + j;
    int row = idx >> 7, k = idx & 127;
    *(u16*)((char*)hbuf[0] + SW(row * 256 + k * 2, row)) = f2bf_bits(h0[(n0 + row) * 128 + k]);
    dsh[idx] = done[(idx >> 3) * 2048 + n0 + (idx & 7)];
  }

  // loop-invariant LDS offsets
  int offr[4];                       // 8-row tiles (h, x): row = cl
  #pragma unroll
  for (int c = 0; c < 4; ++c) offr[c] = SW(cl * 256 + 16 * q + 64 * c, cl);
  int offp[4];                       // 16-row pair tiles (x1p): row = col
  #pragma unroll
  for (int c = 0; c < 4; ++c) offp[c] = SW(col * 256 + 16 * q + 64 * c, col);
  const int wcol2 = (16 * w + col) * 2;
  const int offw0 = SW(rbase * 256 + wcol2, rbase);
  const int offw1 = SW((rbase + 1) * 256 + wcol2, rbase + 1);
  int swoff[4];                      // X1-pair writes: rows m=4q+r (0..15), all lanes
  #pragma unroll
  for (int r = 0; r < 4; ++r) { int m = 4 * q + r; swoff[r] = SW(m * 256 + wcol2, m); }
  int swx[4];                        // X2-pair writes: row (m&7) in x-tile
  #pragma unroll
  for (int r = 0; r < 4; ++r) { int mm = (4 * q + r) & 7; swx[r] = SW(mm * 256 + wcol2, mm); }

  // obs addressing: lane reads batch row n0+cl, k = 32c+8q+2p (pairs; zeroed >=54)
  const long obl = (long)(n0 + cl) * 54;
  int koff[8]; bool kval[8];
  #pragma unroll
  for (int c = 0; c < 2; ++c)
    #pragma unroll
    for (int p = 0; p < 4; ++p) {
      int i = c * 4 + p, kk = 32 * c + 8 * q + 2 * p;
      kval[i] = (kk < 54); koff[i] = kval[i] ? kk : 0;
    }

  // H store pointers
  u16* hp0 = H + (long)(n0 + rbase) * 128 + 16 * w + col;
  u16* hp1 = H + (long)(n0 + rbase + 1) * 128 + 16 * w + col;

  // ---- MLP helpers (pair form) ----
  auto OBSROW = [&](int trow, float2 (&o)[8]) {   // per-lane timestep row
    const float* obsT = obs + (long)trow * 110592 + obl;
    #pragma unroll
    for (int i = 0; i < 8; ++i) o[i] = *(const float2*)(obsT + koff[i]);
  };
  auto X1CP = [&](const float2 (&o)[8], u16* dst) {  // pair X1: all lanes write
    b16x8 a0[2];
    #pragma unroll
    for (int c = 0; c < 2; ++c)
      #pragma unroll
      for (int p = 0; p < 4; ++p) {
        int i = c * 4 + p;
        a0[c][2 * p]     = (__bf16)(kval[i] ? o[i].x : 0.f);
        a0[c][2 * p + 1] = (__bf16)(kval[i] ? o[i].y : 0.f);
      }
    f32x4 a = fzero4();
    a = MFMA16(a0[0], w1f[0], a);
    a = MFMA16(a0[1], w1f[1], a);
    #pragma unroll
    for (int r = 0; r < 4; ++r)
      *(u16*)((char*)dst + swoff[r]) = f2bf_bits(fmaxf(a[r] + b1r, 0.f));
  };
  auto X2P = [&](const u16* src, int sbase) {     // pair X2: rows 0-7 -> slot sbase, 8-15 -> sbase+1
    b16x8 a1[4];
    #pragma unroll
    for (int c = 0; c < 4; ++c) a1[c] = *(const b16x8*)((const char*)src + offp[c]);
    f32x4 a = fzero4();
    #pragma unroll
    for (int c = 0; c < 4; ++c) a = MFMA16(a1[c], w2f[c], a);
    u16* dst = xtl[sbase + (q >> 1)];
    #pragma unroll
    for (int r = 0; r < 4; ++r)
      *(u16*)((char*)dst + swx[r]) = f2bf_bits(fmaxf(a[r] + b2r, 0.f));
  };

  // ---- prologue: X1 pairs (0,1)->slot0, (2,3)->slot1; x(0),x(1); accA=bias+x(0) ----
  __syncthreads();                         // h0/dsh staged
  { float2 o[8]; OBSROW(0 + (col >> 3), o); X1CP(o, x1p[0]); }   // X1 pair (0,1)
  { float2 o[8]; OBSROW(2 + (col >> 3), o); X1CP(o, x1p[1]); }   // X1 pair (2,3)
  __syncthreads();
  X2P(x1p[0], 0);                          // x(0)->slot0, x(1)->slot1
  __syncthreads();
  f32x4 accA[4], accB[4];
  {
    b16x8 xa[4];
    #pragma unroll
    for (int c = 0; c < 4; ++c) xa[c] = *(const b16x8*)((const char*)xtl[0] + offr[c]);
    #pragma unroll
    for (int g = 0; g < 4; ++g) { f32x4 z; z[0]=gbr[g]; z[1]=gbr[g]; z[2]=gbr[g]; z[3]=gbr[g]; accA[g] = z; }
    #pragma unroll
    for (int g = 0; g < 4; ++g)
      #pragma unroll
      for (int c = 0; c < 4; ++c)
        accA[g] = MFMA16(xa[c], wih[g][c], accA[g]);
  }

  int dC0 = 0, dC1 = 0;
  float hv0 = 0.f, hv1 = 0.f;

// step core: maskless h-MFMA (hbuf pre-masked on write) -> cell -> masked h write.
// dC0/dC1 at cell time = done[T-1] (masks c); after reload = done[T] (masks write).
#define LCORE(T_, RB, WB, AC)                                                        \
    b16x8 ha[4];                                                                     \
    _Pragma("unroll") for (int c = 0; c < 4; ++c)                                    \
      ha[c] = *(const b16x8*)((const char*)(RB) + offr[c]);                          \
    if (dC0) cc0 = 0.f;                                                              \
    if (dC1) cc1 = 0.f;                                                              \
    __builtin_amdgcn_s_setprio(1);                                                   \
    _Pragma("unroll") for (int g = 0; g < 4; ++g)                                    \
      _Pragma("unroll") for (int c = 0; c < 4; ++c)                                  \
        AC[g] = MFMA16(ha[c], whh[g][c], AC[g]);                                     \
    __builtin_amdgcn_s_setprio(0);                                                   \
    dC0 = dsh[(T_) * 8 + rbase];                                                     \
    dC1 = dsh[(T_) * 8 + rbase + 1];                                                 \
    _Pragma("unroll") for (int g = 0; g < 4; ++g) {                                  \
      asm volatile("v_permlane32_swap_b32 %0, %1" : "+v"(AC[g][0]), "+v"(AC[g][2])); \
      asm volatile("v_permlane32_swap_b32 %0, %1" : "+v"(AC[g][1]), "+v"(AC[g][3])); \
    }                                                                                \
    cellf(AC[0][0], AC[1][0], AC[2][0], AC[3][0], cc0, hv0);                         \
    cellf(AC[0][1], AC[1][1], AC[2][1], AC[3][1], cc1, hv1);                         \
    { u32 pk;                                                                        \
      asm("v_cvt_pk_bf16_f32 %0, %1, %2" : "=v"(pk) : "v"(hv0), "v"(hv1));           \
      *(u16*)((char*)(WB) + offw0) = dC0 ? (u16)0 : (u16)pk;                         \
      *(u16*)((char*)(WB) + offw1) = dC1 ? (u16)0 : (u16)(pk >> 16);                 \
      *hp0 = (u16)pk; *hp1 = (u16)(pk >> 16);                                        \
      hp0 += 262144; hp1 += 262144; }

#define ANFILL(AN, XSLOT)                                                            \
    { b16x8 xa[4];                                                                   \
      _Pragma("unroll") for (int c = 0; c < 4; ++c)                                  \
        xa[c] = *(const b16x8*)((const char*)xtl[XSLOT] + offr[c]);                  \
      _Pragma("unroll") for (int g = 0; g < 4; ++g) {                                \
        f32x4 z; z[0]=gbr[g]; z[1]=gbr[g]; z[2]=gbr[g]; z[3]=gbr[g]; AN[g] = z; }    \
      __builtin_amdgcn_s_setprio(1);                                                 \
      _Pragma("unroll") for (int g = 0; g < 4; ++g)                                  \
        _Pragma("unroll") for (int c = 0; c < 4; ++c)                                \
          AN[g] = MFMA16(xa[c], wih[g][c], AN[g]);                                   \
      __builtin_amdgcn_s_setprio(0);                                                 \
    }

// even step: X2P (pair (T+2,T+3) from X1RD) + ANFILL
#define LSTEP_E(T_, RB, WB, AC, AN, X1RD, XSLOT, SBASE) {                            \
    LCORE(T_, RB, WB, AC)                                                            \
    X2P(X1RD, SBASE);                                                                \
    ANFILL(AN, XSLOT)                                                                \
    bar_lgkm();                                                                      \
  }

// odd step: obs pair load (top) + ANFILL + X1CP (pair (T+3,T+4) -> X1WR)
#define LSTEP_O(T_, RB, WB, AC, AN, X1WR, XSLOT) {                                   \
    float2 o_[8];                                                                    \
    { int t3 = (T_) + 3 + (col >> 3); if (t3 > 127) t3 = 127; OBSROW(t3, o_); }      \
    LCORE(T_, RB, WB, AC)                                                            \
    ANFILL(AN, XSLOT)                                                                \
    X1CP(o_, X1WR);                                                                  \
    bar_lgkm();                                                                      \
  }

  for (int tb = 0; tb < 128; tb += 4) {
    LSTEP_E(tb,     hbuf[0], hbuf[1], accA, accB, x1p[1], 1, 2)   // X2P reads pair (tb+2,tb+3)
    LSTEP_O(tb + 1, hbuf[1], hbuf[0], accB, accA, x1p[0], 2)      // X1CP writes pair (tb+4,tb+5)
    LSTEP_E(tb + 2, hbuf[0], hbuf[1], accA, accB, x1p[0], 3, 0)   // X2P reads pair (tb+4,tb+5)
    LSTEP_O(tb + 3, hbuf[1], hbuf[0], accB, accA, x1p[1], 0)      // X1CP writes pair (tb+6,tb+7)
  }
#undef LSTEP_E
#undef LSTEP_O
#undef LCORE
#undef ANFILL

  // final hT / cT (f32), 2 rows per lane
  {
    int k = 16 * w + col;
    out[1835008 + (n0 + rbase) * 128 + k]     = hv0;
    out[1835008 + (n0 + rbase + 1) * 128 + k] = hv1;
    out[2097152 + (n0 + rbase) * 128 + k]     = cc0;
    out[2097152 + (n0 + rbase + 1) * 128 + k] = cc1;
  }

  // drain all H stores from every wave, then compute heads from own (L2-hot) H slice
  __syncthreads();
  {
    b16x8 wh[4];
    #pragma unroll
    for (int c = 0; c < 4; ++c) wh[c] = *(const b16x8*)(Whb + col * 128 + 8 * q + 32 * c);
    const float hb = (col < 6) ? bp[col] : ((col == 6) ? bv[0] : 0.f);
    #pragma unroll
    for (int i = 0; i < 8; ++i) {
      int t0 = 16 * w + 2 * i;
      const u16* hsrc = H + ((long)(t0 + (col >> 3)) * 2048 + n0 + (col & 7)) * 128 + 8 * q;
      b16x8 a[4];
      #pragma unroll
      for (int c = 0; c < 4; ++c) a[c] = *(const b16x8*)(hsrc + 32 * c);
      f32x4 hacc = fzero4();
      #pragma unroll
      for (int c = 0; c < 4; ++c) hacc = MFMA16(a[c], wh[c], hacc);
      #pragma unroll
      for (int r = 0; r < 4; ++r) {
        int m = 4 * q + r;
        int tt = t0 + (m >> 3);
        int n = n0 + (m & 7);
        float v = hacc[r] + hb;
        if (col < 6)       out[(tt * 2048 + n) * 6 + col] = v;
        else if (col == 6) out[1572864 + tt * 2048 + n] = v;
      }
    }
  }
}

extern "C" void kernel_launch(void* const* d_in, const int* in_sizes, int n_in,
                              void* d_out, int out_size, void* d_ws, size_t ws_size,
                              hipStream_t stream) {
  const float* obs  = (const float*)d_in[0];
  const float* h0   = (const float*)d_in[1];
  const float* c0   = (const float*)d_in[2];
  const int*   done = (const int*)d_in[3];
  const float* W1   = (const float*)d_in[4];
  const float* b1   = (const float*)d_in[5];
  const float* W2   = (const float*)d_in[6];
  const float* b2   = (const float*)d_in[7];
  const float* Wih  = (const float*)d_in[8];
  const float* Whh  = (const float*)d_in[9];
  const float* bih  = (const float*)d_in[10];
  const float* bhh  = (const float*)d_in[11];
  const float* Wp   = (const float*)d_in[12];
  const float* bp   = (const float*)d_in[13];
  const float* Wv   = (const float*)d_in[14];
  const float* bv   = (const float*)d_in[15];

  char* ws = (char*)d_ws;
  u16*   H    = (u16*)(ws);                                      // 67108864 B
  u16*   W1b  = (u16*)(ws + 67108864);                           // 16384 B
  u16*   W2b  = (u16*)(ws + 67108864 + 16384);                   // 32768 B
  u16*   Wihb = (u16*)(ws + 67108864 + 16384 + 32768);           // 131072 B
  u16*   Whhb = (u16*)(ws + 67108864 + 16384 + 32768 + 131072);  // 131072 B
  u16*   Whb  = (u16*)(ws + 67108864 + 16384 + 32768 + 262144);  // 4096 B
  float* gbp  = (float*)(ws + 67108864 + 16384 + 32768 + 262144 + 4096);
  float* out  = (float*)d_out;

  hipLaunchKernelGGL(prep_kernel, dim3(256), dim3(256), 0, stream,
                     W1, W2, Wih, Whh, Wp, Wv, bih, bhh, W1b, W2b, Wihb, Whhb, Whb, gbp);
  hipLaunchKernelGGL(lstm_fused_kernel, dim3(256), dim3(512), 0, stream,
                     obs, h0, c0, done, W1b, W2b, Wihb, Whhb, Whb, gbp, b1, b2, bp, bv, H, out);
}